// Round 4
// baseline (1121.170 us; speedup 1.0000x reference)
//
#include <hip/hip_runtime.h>
#include <hip/hip_bf16.h>
#include <cstdint>
#include <cstddef>

constexpr int F_IN = 64;
constexpr int HID  = 128;

__device__ __forceinline__ float bf2f(unsigned short u) {
  return __uint_as_float((unsigned)u << 16);
}

// ================= CSR build via 1024-way bucketing =================
// bucket b covers dsts [b*128, (b+1)*128)

__global__ __launch_bounds__(256) void k_bhist(const int* __restrict__ ei,
                                               int* __restrict__ bcnt, int E, int n) {
  __shared__ int hist[1024];
  int t = threadIdx.x;
  for (int k = t; k < 1024; k += 256) hist[k] = 0;
  __syncthreads();
  int tot = E + n;
  for (int i = blockIdx.x * 256 + t; i < tot; i += gridDim.x * 256) {
    int d = (i < E) ? ei[E + i] : (i - E);
    atomicAdd(&hist[d >> 7], 1);
  }
  __syncthreads();
  for (int k = t; k < 1024; k += 256)
    if (hist[k]) atomicAdd(&bcnt[k], hist[k]);
}

// single block: exclusive scan of bcnt[nb] -> boff[0..nb], init bcur
__global__ __launch_bounds__(1024) void k_bscan(const int* __restrict__ bcnt,
                                                int* __restrict__ boff,
                                                int* __restrict__ bcur, int nb) {
  __shared__ int tmp[1024];
  int t = threadIdx.x;
  int v = (t < nb) ? bcnt[t] : 0;
  tmp[t] = v;
  __syncthreads();
  #pragma unroll
  for (int off = 1; off < 1024; off <<= 1) {
    int x = tmp[t];
    int add = (t >= off) ? tmp[t - off] : 0;
    __syncthreads();
    tmp[t] = x + add;
    __syncthreads();
  }
  if (t < nb) {
    int ex = tmp[t] - v;
    boff[t] = ex;
    bcur[t] = ex;
    if (t == nb - 1) boff[nb] = tmp[t];
  }
}

__global__ __launch_bounds__(256) void k_bscat(const int* __restrict__ ei,
                                               int* __restrict__ bcur,
                                               uint2* __restrict__ pairs, int E, int n) {
  int tot = E + n;
  for (int i = blockIdx.x * 256 + threadIdx.x; i < tot; i += gridDim.x * 256) {
    int s = (i < E) ? ei[i]     : (i - E);
    int d = (i < E) ? ei[E + i] : (i - E);
    int pos = atomicAdd(&bcur[d >> 7], 1);
    pairs[pos] = make_uint2((unsigned)s, (unsigned)d);
  }
}

// block per bucket: local per-dst counts -> row_off + final csr scatter
__global__ __launch_bounds__(256) void k_bfin(const uint2* __restrict__ pairs,
                                              const int* __restrict__ boff,
                                              int* __restrict__ row_off,
                                              int* __restrict__ csr_src,
                                              int n, int tot) {
  __shared__ int ldeg[128];
  __shared__ int lcur[128];
  int b = blockIdx.x;
  int t = threadIdx.x;
  int pb = boff[b], pe = boff[b + 1];
  if (t < 128) ldeg[t] = 0;
  __syncthreads();
  for (int j = pb + t; j < pe; j += 256)
    atomicAdd(&ldeg[pairs[j].y & 127], 1);
  __syncthreads();
  int cnt = (t < 128) ? ldeg[t] : 0;
  // inclusive Hillis-Steele scan over the 128 counts
  for (int off = 1; off < 128; off <<= 1) {
    int add = (t < 128 && t >= off) ? ldeg[t - off] : 0;
    __syncthreads();
    if (t < 128) ldeg[t] += add;
    __syncthreads();
  }
  if (t < 128) {
    int base = pb + ldeg[t] - cnt;   // exclusive
    lcur[t] = base;
    int idx = (b << 7) + t;
    if (idx < n) row_off[idx] = base;
  }
  if (b == 0 && t == 255) row_off[n] = tot;
  __syncthreads();
  for (int j = pb + t; j < pe; j += 256) {
    uint2 pr = pairs[j];
    int pos = atomicAdd(&lcur[pr.y & 127], 1);
    csr_src[pos] = (int)pr.x;
  }
}

// ============ GEMM: [n,K] fp32 @ [K,128] fp32 -> [n,128] bf16 ============
template<int K>
__global__ __launch_bounds__(256) void k_gemm(const float* __restrict__ X,
                                              const float* __restrict__ W,
                                              __hip_bfloat16* __restrict__ Y, int n) {
  __shared__ float Xt[K][36];   // 32 rows used, +4 pad keeps 16B align & breaks bank stride
  int t = threadIdx.x;
  int r0 = blockIdx.x * 32;
  for (int i = t; i < 32 * K; i += 256) {
    int r = i / K, k = i - r * K;
    int gr = r0 + r;
    Xt[k][r] = (gr < n) ? X[gr * K + k] : 0.f;
  }
  __syncthreads();
  int c  = t & 127;
  int rb = (t >> 7) * 16;
  float acc[16] = {};
  for (int k = 0; k < K; ++k) {
    float w = W[k * 128 + c];
    const float* xr = &Xt[k][rb];
    float4 x0 = *(const float4*)(xr);
    float4 x1 = *(const float4*)(xr + 4);
    float4 x2 = *(const float4*)(xr + 8);
    float4 x3 = *(const float4*)(xr + 12);
    acc[0]  += x0.x * w; acc[1]  += x0.y * w; acc[2]  += x0.z * w; acc[3]  += x0.w * w;
    acc[4]  += x1.x * w; acc[5]  += x1.y * w; acc[6]  += x1.z * w; acc[7]  += x1.w * w;
    acc[8]  += x2.x * w; acc[9]  += x2.y * w; acc[10] += x2.z * w; acc[11] += x2.w * w;
    acc[12] += x3.x * w; acc[13] += x3.y * w; acc[14] += x3.z * w; acc[15] += x3.w * w;
  }
  #pragma unroll
  for (int j = 0; j < 16; ++j) {
    int gr = r0 + rb + j;
    if (gr < n) Y[gr * 128 + c] = __float2bfloat16(acc[j]);
  }
}

// ---------------- alpha: wave per node, coalesced bf16 reads ----------------
template<int LOGC>
__global__ __launch_bounds__(256) void k_alpha(const __hip_bfloat16* __restrict__ H,
    const float* __restrict__ a_s, const float* __restrict__ a_d,
    float* __restrict__ AS, float* __restrict__ AD, int n) {
  int wid  = (int)((blockIdx.x * (size_t)blockDim.x + threadIdx.x) >> 6);
  int lane = threadIdx.x & 63;
  if (wid >= n) return;
  constexpr int SEG = 1 << (LOGC - 1);
  constexpr int NH  = HID >> LOGC;
  int c = 2 * lane;
  ushort2 u = *(const ushort2*)((const unsigned short*)H + wid * HID + c);
  float h0 = bf2f(u.x), h1 = bf2f(u.y);
  float s1 = h0 * a_s[c] + h1 * a_s[c + 1];
  float s2 = h0 * a_d[c] + h1 * a_d[c + 1];
  #pragma unroll
  for (int off = 1; off < SEG; off <<= 1) {
    s1 += __shfl_xor(s1, off);
    s2 += __shfl_xor(s2, off);
  }
  if ((lane & (SEG - 1)) == 0) {
    int h = lane / SEG;
    AS[wid * NH + h] = s1;
    AD[wid * NH + h] = s2;
  }
}

// ---- GAT aggregation (no-max softmax) + bias + ELU + LayerNorm + residual ----
template<int LOGC>
__global__ __launch_bounds__(256) void k_agg_post(const __hip_bfloat16* __restrict__ H,
    const int* __restrict__ row_off, const int* __restrict__ csr_src,
    const float* __restrict__ AS, const float* __restrict__ AD,
    const float* __restrict__ bias, const float* __restrict__ RES,
    const float* __restrict__ gamma, const float* __restrict__ beta,
    float* __restrict__ Y, int n, int has_res) {
  int wid  = (int)((blockIdx.x * (size_t)blockDim.x + threadIdx.x) >> 6);
  int lane = threadIdx.x & 63;
  if (wid >= n) return;
  constexpr int NH = HID >> LOGC;
  int c = 2 * lane;                    // lane owns channels c, c+1 (same head)
  int h = c >> LOGC;
  float adv = AD[wid * NH + h];
  int jb = row_off[wid], je = row_off[wid + 1];
  float den = 0.f, a0 = 0.f, a1 = 0.f;
  const unsigned short* Hu = (const unsigned short*)H;
  int s_next = (jb < je) ? csr_src[jb] : 0;
  for (int j = jb; j < je; ++j) {
    int s = s_next;
    if (j + 1 < je) s_next = csr_src[j + 1];
    float e = AS[s * NH + h] + adv;
    e = (e > 0.f) ? e : 0.2f * e;            // leaky_relu(0.2)
    float p = __expf(e);                     // |e| small by construction: no max needed
    ushort2 u = *(const ushort2*)(Hu + (s << 7) + c);
    den += p;
    a0 = fmaf(p, bf2f(u.x), a0);
    a1 = fmaf(p, bf2f(u.y), a1);
  }
  float inv = 1.f / (den + 1e-16f);
  float t0 = a0 * inv + bias[c];
  float t1 = a1 * inv + bias[c + 1];
  float e0 = t0 > 0.f ? t0 : __expf(t0) - 1.f;   // ELU
  float e1 = t1 > 0.f ? t1 : __expf(t1) - 1.f;
  float s1 = e0 + e1, s2 = e0 * e0 + e1 * e1;
  #pragma unroll
  for (int off = 32; off >= 1; off >>= 1) {
    s1 += __shfl_xor(s1, off);
    s2 += __shfl_xor(s2, off);
  }
  float mu  = s1 * (1.f / 128.f);
  float var = s2 * (1.f / 128.f) - mu * mu;
  float rs  = rsqrtf(var + 1e-5f);
  int base = wid * HID;
  float r0 = 0.f, r1 = 0.f;
  if (has_res) { float2 rv = *(const float2*)(RES + base + c); r0 = rv.x; r1 = rv.y; }
  float2 o;
  o.x = (e0 - mu) * rs * gamma[c]     + beta[c]     + r0;
  o.y = (e1 - mu) * rs * gamma[c + 1] + beta[c + 1] + r1;
  *(float2*)(Y + base + c) = o;
}

// ---------------- global mean pool: wave per graph (batch is sorted) ----------------
__global__ __launch_bounds__(256) void k_pool_seg(const float* __restrict__ Hf,
    const int* __restrict__ batch, float* __restrict__ pool, int n, int G) {
  int wid  = (int)((blockIdx.x * (size_t)blockDim.x + threadIdx.x) >> 6);
  int lane = threadIdx.x & 63;
  if (wid >= G) return;
  int lo = 0, hi = n;
  while (lo < hi) { int mid = (lo + hi) >> 1; if (batch[mid] < wid) lo = mid + 1; else hi = mid; }
  int start = lo;
  hi = n;
  while (lo < hi) { int mid = (lo + hi) >> 1; if (batch[mid] < wid + 1) lo = mid + 1; else hi = mid; }
  int end = lo;
  int c = 2 * lane;
  float s0 = 0.f, s1 = 0.f;
  for (int i = start; i < end; ++i) {
    float2 v = *(const float2*)(Hf + (size_t)i * HID + c);
    s0 += v.x; s1 += v.y;
  }
  float inv = 1.f / (float)max(end - start, 1);
  pool[(size_t)wid * HID + c]     = s0 * inv;
  pool[(size_t)wid * HID + c + 1] = s1 * inv;
}

// ---------------- small MLP: [rows,128] @ [128,128] + b (opt ELU) ----------------
__global__ void k_mlp(const float* __restrict__ X, const float* __restrict__ Wt,
                      const float* __restrict__ bb, float* __restrict__ Y,
                      int rows, int do_elu) {
  int i = blockIdx.x * blockDim.x + threadIdx.x;
  if (i >= rows * HID) return;
  int r = i >> 7, c = i & 127;
  const float* xr = X + (size_t)r * HID;
  float acc = bb[c];
  for (int k = 0; k < HID; ++k) acc += xr[k] * Wt[k * HID + c];
  if (do_elu) acc = acc > 0.f ? acc : __expf(acc) - 1.f;
  Y[i] = acc;
}

extern "C" void kernel_launch(void* const* d_in, const int* in_sizes, int n_in,
                              void* d_out, int out_size, void* d_ws, size_t ws_size,
                              hipStream_t stream) {
  const float* x   = (const float*)d_in[0];
  const int*   ei  = (const int*)d_in[1];
  const int*   bat = (const int*)d_in[2];
  const float* W1  = (const float*)d_in[3];
  const float* as1 = (const float*)d_in[4];
  const float* ad1 = (const float*)d_in[5];
  const float* b1  = (const float*)d_in[6];
  const float* W2  = (const float*)d_in[7];
  const float* as2 = (const float*)d_in[8];
  const float* ad2 = (const float*)d_in[9];
  const float* b2  = (const float*)d_in[10];
  const float* W3  = (const float*)d_in[11];
  const float* as3 = (const float*)d_in[12];
  const float* ad3 = (const float*)d_in[13];
  const float* b3  = (const float*)d_in[14];
  const float* g1  = (const float*)d_in[15];
  const float* be1 = (const float*)d_in[16];
  const float* g2  = (const float*)d_in[17];
  const float* be2 = (const float*)d_in[18];
  const float* g3  = (const float*)d_in[19];
  const float* be3 = (const float*)d_in[20];
  const float* lw1 = (const float*)d_in[21];
  const float* lb1 = (const float*)d_in[22];
  const float* lw2 = (const float*)d_in[23];
  const float* lb2 = (const float*)d_in[24];

  int N = in_sizes[0] / F_IN;
  int E = in_sizes[1] / 2;
  int G = out_size / HID;
  int tot = E + N;
  int nb  = (N + 127) >> 7;          // buckets (<=1024)

  char* p = (char*)d_ws;
  auto alloc = [&](size_t bytes) { char* r = p; p += (bytes + 511) & ~(size_t)511; return r; };
  int*   bcnt    = (int*)  alloc(1024 * 4);
  int*   boff    = (int*)  alloc(1025 * 4);
  int*   bcur    = (int*)  alloc(1024 * 4);
  int*   row_off = (int*)  alloc((size_t)(N + 1) * 4);
  int*   csr_src = (int*)  alloc((size_t)tot * 4);
  uint2* pairs   = (uint2*)alloc((size_t)tot * 8);
  float* AS      = (float*)alloc((size_t)N * 8 * 4);
  float* AD      = (float*)alloc((size_t)N * 8 * 4);
  __hip_bfloat16* Hb = (__hip_bfloat16*)alloc((size_t)N * HID * 2);
  float* F0      = (float*)alloc((size_t)N * HID * 4);
  float* F1      = (float*)alloc((size_t)N * HID * 4);
  float* pool    = (float*)alloc((size_t)G * HID * 4);
  float* t1      = (float*)alloc((size_t)G * HID * 4);

  hipMemsetAsync(bcnt, 0, 1024 * 4, stream);

  k_bhist<<<1024, 256, 0, stream>>>(ei, bcnt, E, N);
  k_bscan<<<1, 1024, 0, stream>>>(bcnt, boff, bcur, nb);
  k_bscat<<<1024, 256, 0, stream>>>(ei, bcur, pairs, E, N);
  k_bfin <<<nb, 256, 0, stream>>>(pairs, boff, row_off, csr_src, N, tot);

  int gb = (N + 31) / 32;                 // GEMM blocks (32 rows each)
  int nw = (N + 3) / 4;                   // wave-per-node kernels: 4 waves/block

  // ---- layer 1: x[N,64] -> Hb -> agg+post -> F0
  k_gemm<64><<<gb, 256, 0, stream>>>(x, W1, Hb, N);
  k_alpha<4><<<nw, 256, 0, stream>>>(Hb, as1, ad1, AS, AD, N);
  k_agg_post<4><<<nw, 256, 0, stream>>>(Hb, row_off, csr_src, AS, AD, b1,
                                        nullptr, g1, be1, F0, N, 0);

  // ---- layer 2: F0 -> Hb -> agg+post(+F0) -> F1
  k_gemm<128><<<gb, 256, 0, stream>>>(F0, W2, Hb, N);
  k_alpha<7><<<nw, 256, 0, stream>>>(Hb, as2, ad2, AS, AD, N);
  k_agg_post<7><<<nw, 256, 0, stream>>>(Hb, row_off, csr_src, AS, AD, b2,
                                        F0, g2, be2, F1, N, 1);

  // ---- layer 3: F1 -> Hb -> agg+post(+F1) -> F0
  k_gemm<128><<<gb, 256, 0, stream>>>(F1, W3, Hb, N);
  k_alpha<7><<<nw, 256, 0, stream>>>(Hb, as3, ad3, AS, AD, N);
  k_agg_post<7><<<nw, 256, 0, stream>>>(Hb, row_off, csr_src, AS, AD, b3,
                                        F1, g3, be3, F0, N, 1);

  // ---- pool + MLP head
  k_pool_seg<<<(G + 3) / 4, 256, 0, stream>>>(F0, bat, pool, N, G);
  k_mlp<<<(G * HID + 255) / 256, 256, 0, stream>>>(pool, lw1, lb1, t1, G, 1);
  k_mlp<<<(G * HID + 255) / 256, 256, 0, stream>>>(t1, lw2, lb2, (float*)d_out, G, 0);
}

// Round 5
// 707.914 us; speedup vs baseline: 1.5838x; 1.5838x over previous
//
#include <hip/hip_runtime.h>
#include <hip/hip_bf16.h>
#include <cstdint>
#include <cstddef>

constexpr int F_IN = 64;
constexpr int HID  = 128;
constexpr int SCHUNK = 4096;   // edges per scatter block (16/thread)

__device__ __forceinline__ float bf2f(unsigned short u) {
  return __uint_as_float((unsigned)u << 16);
}

// ================= CSR build via 1024-way bucketing =================
// bucket b covers dsts [b*128, (b+1)*128)

__global__ __launch_bounds__(256) void k_bhist(const int* __restrict__ ei,
                                               int* __restrict__ bcnt, int E, int n) {
  __shared__ int hist[1024];
  int t = threadIdx.x;
  for (int k = t; k < 1024; k += 256) hist[k] = 0;
  __syncthreads();
  int tot = E + n;
  for (int i = blockIdx.x * 256 + t; i < tot; i += gridDim.x * 256) {
    int d = (i < E) ? ei[E + i] : (i - E);
    atomicAdd(&hist[d >> 7], 1);
  }
  __syncthreads();
  for (int k = t; k < 1024; k += 256)
    if (hist[k]) atomicAdd(&bcnt[k], hist[k]);
}

// single block: exclusive scan of bcnt[nb] -> boff[0..nb], init bcur
__global__ __launch_bounds__(1024) void k_bscan(const int* __restrict__ bcnt,
                                                int* __restrict__ boff,
                                                int* __restrict__ bcur, int nb) {
  __shared__ int tmp[1024];
  int t = threadIdx.x;
  int v = (t < nb) ? bcnt[t] : 0;
  tmp[t] = v;
  __syncthreads();
  #pragma unroll
  for (int off = 1; off < 1024; off <<= 1) {
    int x = tmp[t];
    int add = (t >= off) ? tmp[t - off] : 0;
    __syncthreads();
    tmp[t] = x + add;
    __syncthreads();
  }
  if (t < nb) {
    int ex = tmp[t] - v;
    boff[t] = ex;
    bcur[t] = ex;
    if (t == nb - 1) boff[nb] = tmp[t];
  }
}

// block-aggregated scatter: LDS histogram -> one global atomic per (block,bucket)
// -> contiguous per-block ranges (no same-address storms, no write amplification)
__global__ __launch_bounds__(256) void k_bscat(const int* __restrict__ ei,
                                               int* __restrict__ bcur,
                                               uint2* __restrict__ pairs, int E, int n) {
  __shared__ int lh[1024];   // local hist, then global base per bucket
  __shared__ int lc[1024];   // local cursor
  int t = threadIdx.x;
  int tot = E + n;
  int start = blockIdx.x * SCHUNK;
  if (start >= tot) return;
  int end = min(start + SCHUNK, tot);
  for (int k = t; k < 1024; k += 256) { lh[k] = 0; lc[k] = 0; }
  __syncthreads();
  int dreg[SCHUNK / 256];
  #pragma unroll
  for (int q = 0; q < SCHUNK / 256; ++q) {
    int i = start + q * 256 + t;
    int d = (i < end) ? ((i < E) ? ei[E + i] : (i - E)) : -1;
    dreg[q] = d;
    if (d >= 0) atomicAdd(&lh[d >> 7], 1);
  }
  __syncthreads();
  for (int k = t; k < 1024; k += 256) {
    int c = lh[k];
    lh[k] = (c > 0) ? atomicAdd(&bcur[k], c) : 0;
  }
  __syncthreads();
  #pragma unroll
  for (int q = 0; q < SCHUNK / 256; ++q) {
    int i = start + q * 256 + t;
    int d = dreg[q];
    if (d < 0) continue;
    int s = (i < E) ? ei[i] : (i - E);
    int b = d >> 7;
    int loc = atomicAdd(&lc[b], 1);
    pairs[lh[b] + loc] = make_uint2((unsigned)s, (unsigned)d);
  }
}

// block per bucket: local per-dst counts -> row_off + final csr scatter
__global__ __launch_bounds__(256) void k_bfin(const uint2* __restrict__ pairs,
                                              const int* __restrict__ boff,
                                              int* __restrict__ row_off,
                                              int* __restrict__ csr_src,
                                              int n, int tot) {
  __shared__ int ldeg[128];
  __shared__ int lcur[128];
  int b = blockIdx.x;
  int t = threadIdx.x;
  int pb = boff[b], pe = boff[b + 1];
  if (t < 128) ldeg[t] = 0;
  __syncthreads();
  for (int j = pb + t; j < pe; j += 256)
    atomicAdd(&ldeg[pairs[j].y & 127], 1);
  __syncthreads();
  int cnt = (t < 128) ? ldeg[t] : 0;
  for (int off = 1; off < 128; off <<= 1) {
    int add = (t < 128 && t >= off) ? ldeg[t - off] : 0;
    __syncthreads();
    if (t < 128) ldeg[t] += add;
    __syncthreads();
  }
  if (t < 128) {
    int base = pb + ldeg[t] - cnt;   // exclusive
    lcur[t] = base;
    int idx = (b << 7) + t;
    if (idx < n) row_off[idx] = base;
  }
  if (b == 0 && t == 255) row_off[n] = tot;
  __syncthreads();
  for (int j = pb + t; j < pe; j += 256) {
    uint2 pr = pairs[j];
    int pos = atomicAdd(&lcur[pr.y & 127], 1);
    csr_src[pos] = (int)pr.x;
  }
}

// ============ GEMM: [n,K] fp32 @ [K,128] fp32 -> [n,128] bf16 ============
template<int K>
__global__ __launch_bounds__(256) void k_gemm(const float* __restrict__ X,
                                              const float* __restrict__ W,
                                              __hip_bfloat16* __restrict__ Y, int n) {
  __shared__ float Xt[K][36];
  int t = threadIdx.x;
  int r0 = blockIdx.x * 32;
  for (int i = t; i < 32 * K; i += 256) {
    int r = i / K, k = i - r * K;
    int gr = r0 + r;
    Xt[k][r] = (gr < n) ? X[gr * K + k] : 0.f;
  }
  __syncthreads();
  int c  = t & 127;
  int rb = (t >> 7) * 16;
  float acc[16] = {};
  for (int k = 0; k < K; ++k) {
    float w = W[k * 128 + c];
    const float* xr = &Xt[k][rb];
    float4 x0 = *(const float4*)(xr);
    float4 x1 = *(const float4*)(xr + 4);
    float4 x2 = *(const float4*)(xr + 8);
    float4 x3 = *(const float4*)(xr + 12);
    acc[0]  += x0.x * w; acc[1]  += x0.y * w; acc[2]  += x0.z * w; acc[3]  += x0.w * w;
    acc[4]  += x1.x * w; acc[5]  += x1.y * w; acc[6]  += x1.z * w; acc[7]  += x1.w * w;
    acc[8]  += x2.x * w; acc[9]  += x2.y * w; acc[10] += x2.z * w; acc[11] += x2.w * w;
    acc[12] += x3.x * w; acc[13] += x3.y * w; acc[14] += x3.z * w; acc[15] += x3.w * w;
  }
  #pragma unroll
  for (int j = 0; j < 16; ++j) {
    int gr = r0 + rb + j;
    if (gr < n) Y[gr * 128 + c] = __float2bfloat16(acc[j]);
  }
}

// ---------------- alpha: wave per node, coalesced bf16 reads ----------------
template<int LOGC>
__global__ __launch_bounds__(256) void k_alpha(const __hip_bfloat16* __restrict__ H,
    const float* __restrict__ a_s, const float* __restrict__ a_d,
    float* __restrict__ AS, float* __restrict__ AD, int n) {
  int wid  = (int)((blockIdx.x * (size_t)blockDim.x + threadIdx.x) >> 6);
  int lane = threadIdx.x & 63;
  if (wid >= n) return;
  constexpr int SEG = 1 << (LOGC - 1);
  constexpr int NH  = HID >> LOGC;
  int c = 2 * lane;
  ushort2 u = *(const ushort2*)((const unsigned short*)H + wid * HID + c);
  float h0 = bf2f(u.x), h1 = bf2f(u.y);
  float s1 = h0 * a_s[c] + h1 * a_s[c + 1];
  float s2 = h0 * a_d[c] + h1 * a_d[c + 1];
  #pragma unroll
  for (int off = 1; off < SEG; off <<= 1) {
    s1 += __shfl_xor(s1, off);
    s2 += __shfl_xor(s2, off);
  }
  if ((lane & (SEG - 1)) == 0) {
    int h = lane / SEG;
    AS[wid * NH + h] = s1;
    AD[wid * NH + h] = s2;
  }
}

// ---- GAT aggregation (cooperative no-max softmax) + ELU + LN + residual ----
// Per SEG-edge group: lane r computes p for edge j0+r (one exp per SEG edges),
// then (s,p) broadcast via shfl; accumulation per lane on its 2 channels.
template<int LOGC>
__global__ __launch_bounds__(256) void k_agg_post(const __hip_bfloat16* __restrict__ H,
    const int* __restrict__ row_off, const int* __restrict__ csr_src,
    const float* __restrict__ AS, const float* __restrict__ AD,
    const float* __restrict__ bias, const float* __restrict__ RES,
    const float* __restrict__ gamma, const float* __restrict__ beta,
    float* __restrict__ Y, int n, int has_res) {
  int wid  = (int)((blockIdx.x * (size_t)blockDim.x + threadIdx.x) >> 6);
  int lane = threadIdx.x & 63;
  if (wid >= n) return;
  constexpr int NH  = HID >> LOGC;
  constexpr int SEG = 1 << (LOGC - 1);     // lanes per head
  int c = 2 * lane;                        // lane owns channels c, c+1
  int h = c >> LOGC;
  int r = lane & (SEG - 1);                // edge slot within group
  int hbase = lane & ~(SEG - 1);           // first lane of this head
  float adv = AD[wid * NH + h];
  int jb = row_off[wid], je = row_off[wid + 1];
  float den = 0.f, a0 = 0.f, a1 = 0.f;
  const unsigned short* Hu = (const unsigned short*)H;
  for (int j0 = jb; j0 < je; j0 += SEG) {
    int cnt = min(SEG, je - j0);
    int s_l = 0; float p_l = 0.f;
    if (r < cnt) {
      s_l = csr_src[j0 + r];
      float e = AS[s_l * NH + h] + adv;
      e = (e > 0.f) ? e : 0.2f * e;        // leaky_relu(0.2)
      p_l = __expf(e);                     // |e| small by construction
    }
    for (int k = 0; k < cnt; ++k) {
      int   s  = __shfl(s_l, hbase | k);
      float pk = __shfl(p_l, hbase | k);
      ushort2 u = *(const ushort2*)(Hu + (s << 7) + c);
      den += pk;
      a0 = fmaf(pk, bf2f(u.x), a0);
      a1 = fmaf(pk, bf2f(u.y), a1);
    }
  }
  float inv = 1.f / (den + 1e-16f);
  float t0 = a0 * inv + bias[c];
  float t1 = a1 * inv + bias[c + 1];
  float e0 = t0 > 0.f ? t0 : __expf(t0) - 1.f;   // ELU
  float e1 = t1 > 0.f ? t1 : __expf(t1) - 1.f;
  float s1 = e0 + e1, s2 = e0 * e0 + e1 * e1;
  #pragma unroll
  for (int off = 32; off >= 1; off >>= 1) {
    s1 += __shfl_xor(s1, off);
    s2 += __shfl_xor(s2, off);
  }
  float mu  = s1 * (1.f / 128.f);
  float var = s2 * (1.f / 128.f) - mu * mu;
  float rs  = rsqrtf(var + 1e-5f);
  int base = wid * HID;
  float r0 = 0.f, r1 = 0.f;
  if (has_res) { float2 rv = *(const float2*)(RES + base + c); r0 = rv.x; r1 = rv.y; }
  float2 o;
  o.x = (e0 - mu) * rs * gamma[c]     + beta[c]     + r0;
  o.y = (e1 - mu) * rs * gamma[c + 1] + beta[c + 1] + r1;
  *(float2*)(Y + base + c) = o;
}

// ---------------- global mean pool: wave per graph (batch is sorted) ----------------
__global__ __launch_bounds__(256) void k_pool_seg(const float* __restrict__ Hf,
    const int* __restrict__ batch, float* __restrict__ pool, int n, int G) {
  int wid  = (int)((blockIdx.x * (size_t)blockDim.x + threadIdx.x) >> 6);
  int lane = threadIdx.x & 63;
  if (wid >= G) return;
  int lo = 0, hi = n;
  while (lo < hi) { int mid = (lo + hi) >> 1; if (batch[mid] < wid) lo = mid + 1; else hi = mid; }
  int start = lo;
  hi = n;
  while (lo < hi) { int mid = (lo + hi) >> 1; if (batch[mid] < wid + 1) lo = mid + 1; else hi = mid; }
  int end = lo;
  int c = 2 * lane;
  float s0 = 0.f, s1 = 0.f;
  for (int i = start; i < end; ++i) {
    float2 v = *(const float2*)(Hf + (size_t)i * HID + c);
    s0 += v.x; s1 += v.y;
  }
  float inv = 1.f / (float)max(end - start, 1);
  pool[(size_t)wid * HID + c]     = s0 * inv;
  pool[(size_t)wid * HID + c + 1] = s1 * inv;
}

// ---------------- small MLP: [rows,128] @ [128,128] + b (opt ELU) ----------------
__global__ void k_mlp(const float* __restrict__ X, const float* __restrict__ Wt,
                      const float* __restrict__ bb, float* __restrict__ Y,
                      int rows, int do_elu) {
  int i = blockIdx.x * blockDim.x + threadIdx.x;
  if (i >= rows * HID) return;
  int r = i >> 7, c = i & 127;
  const float* xr = X + (size_t)r * HID;
  float acc = bb[c];
  for (int k = 0; k < HID; ++k) acc += xr[k] * Wt[k * HID + c];
  if (do_elu) acc = acc > 0.f ? acc : __expf(acc) - 1.f;
  Y[i] = acc;
}

extern "C" void kernel_launch(void* const* d_in, const int* in_sizes, int n_in,
                              void* d_out, int out_size, void* d_ws, size_t ws_size,
                              hipStream_t stream) {
  const float* x   = (const float*)d_in[0];
  const int*   ei  = (const int*)d_in[1];
  const int*   bat = (const int*)d_in[2];
  const float* W1  = (const float*)d_in[3];
  const float* as1 = (const float*)d_in[4];
  const float* ad1 = (const float*)d_in[5];
  const float* b1  = (const float*)d_in[6];
  const float* W2  = (const float*)d_in[7];
  const float* as2 = (const float*)d_in[8];
  const float* ad2 = (const float*)d_in[9];
  const float* b2  = (const float*)d_in[10];
  const float* W3  = (const float*)d_in[11];
  const float* as3 = (const float*)d_in[12];
  const float* ad3 = (const float*)d_in[13];
  const float* b3  = (const float*)d_in[14];
  const float* g1  = (const float*)d_in[15];
  const float* be1 = (const float*)d_in[16];
  const float* g2  = (const float*)d_in[17];
  const float* be2 = (const float*)d_in[18];
  const float* g3  = (const float*)d_in[19];
  const float* be3 = (const float*)d_in[20];
  const float* lw1 = (const float*)d_in[21];
  const float* lb1 = (const float*)d_in[22];
  const float* lw2 = (const float*)d_in[23];
  const float* lb2 = (const float*)d_in[24];

  int N = in_sizes[0] / F_IN;
  int E = in_sizes[1] / 2;
  int G = out_size / HID;
  int tot = E + N;
  int nb  = (N + 127) >> 7;          // buckets (<=1024)

  char* p = (char*)d_ws;
  auto alloc = [&](size_t bytes) { char* r = p; p += (bytes + 511) & ~(size_t)511; return r; };
  int*   bcnt    = (int*)  alloc(1024 * 4);
  int*   boff    = (int*)  alloc(1025 * 4);
  int*   bcur    = (int*)  alloc(1024 * 4);
  int*   row_off = (int*)  alloc((size_t)(N + 1) * 4);
  int*   csr_src = (int*)  alloc((size_t)tot * 4);
  uint2* pairs   = (uint2*)alloc((size_t)tot * 8);
  float* AS      = (float*)alloc((size_t)N * 8 * 4);
  float* AD      = (float*)alloc((size_t)N * 8 * 4);
  __hip_bfloat16* Hb = (__hip_bfloat16*)alloc((size_t)N * HID * 2);
  float* F0      = (float*)alloc((size_t)N * HID * 4);
  float* F1      = (float*)alloc((size_t)N * HID * 4);
  float* pool    = (float*)alloc((size_t)G * HID * 4);
  float* t1      = (float*)alloc((size_t)G * HID * 4);

  hipMemsetAsync(bcnt, 0, 1024 * 4, stream);

  int sb = (tot + SCHUNK - 1) / SCHUNK;
  k_bhist<<<256, 256, 0, stream>>>(ei, bcnt, E, N);
  k_bscan<<<1, 1024, 0, stream>>>(bcnt, boff, bcur, nb);
  k_bscat<<<sb, 256, 0, stream>>>(ei, bcur, pairs, E, N);
  k_bfin <<<nb, 256, 0, stream>>>(pairs, boff, row_off, csr_src, N, tot);

  int gb = (N + 31) / 32;                 // GEMM blocks (32 rows each)
  int nw = (N + 3) / 4;                   // wave-per-node kernels: 4 waves/block

  // ---- layer 1: x[N,64] -> Hb -> agg+post -> F0
  k_gemm<64><<<gb, 256, 0, stream>>>(x, W1, Hb, N);
  k_alpha<4><<<nw, 256, 0, stream>>>(Hb, as1, ad1, AS, AD, N);
  k_agg_post<4><<<nw, 256, 0, stream>>>(Hb, row_off, csr_src, AS, AD, b1,
                                        nullptr, g1, be1, F0, N, 0);

  // ---- layer 2: F0 -> Hb -> agg+post(+F0) -> F1
  k_gemm<128><<<gb, 256, 0, stream>>>(F0, W2, Hb, N);
  k_alpha<7><<<nw, 256, 0, stream>>>(Hb, as2, ad2, AS, AD, N);
  k_agg_post<7><<<nw, 256, 0, stream>>>(Hb, row_off, csr_src, AS, AD, b2,
                                        F0, g2, be2, F1, N, 1);

  // ---- layer 3: F1 -> Hb -> agg+post(+F1) -> F0
  k_gemm<128><<<gb, 256, 0, stream>>>(F1, W3, Hb, N);
  k_alpha<7><<<nw, 256, 0, stream>>>(Hb, as3, ad3, AS, AD, N);
  k_agg_post<7><<<nw, 256, 0, stream>>>(Hb, row_off, csr_src, AS, AD, b3,
                                        F1, g3, be3, F0, N, 1);

  // ---- pool + MLP head
  k_pool_seg<<<(G + 3) / 4, 256, 0, stream>>>(F0, bat, pool, N, G);
  k_mlp<<<(G * HID + 255) / 256, 256, 0, stream>>>(pool, lw1, lb1, t1, G, 1);
  k_mlp<<<(G * HID + 255) / 256, 256, 0, stream>>>(t1, lw2, lb2, (float*)d_out, G, 0);
}

// Round 6
// 553.912 us; speedup vs baseline: 2.0241x; 1.2780x over previous
//
#include <hip/hip_runtime.h>
#include <hip/hip_bf16.h>
#include <cstdint>
#include <cstddef>

constexpr int F_IN = 64;
constexpr int HID  = 128;
constexpr int SCHUNK = 4096;   // edges per scatter block (16/thread)

__device__ __forceinline__ float bf2f(unsigned short u) {
  return __uint_as_float((unsigned)u << 16);
}

// ================= CSR build via 1024-way bucketing =================
__global__ __launch_bounds__(256) void k_bhist(const int* __restrict__ ei,
                                               int* __restrict__ bcnt, int E, int n) {
  __shared__ int hist[1024];
  int t = threadIdx.x;
  for (int k = t; k < 1024; k += 256) hist[k] = 0;
  __syncthreads();
  int tot = E + n;
  for (int i = blockIdx.x * 256 + t; i < tot; i += gridDim.x * 256) {
    int d = (i < E) ? ei[E + i] : (i - E);
    atomicAdd(&hist[d >> 7], 1);
  }
  __syncthreads();
  for (int k = t; k < 1024; k += 256)
    if (hist[k]) atomicAdd(&bcnt[k], hist[k]);
}

__global__ __launch_bounds__(1024) void k_bscan(const int* __restrict__ bcnt,
                                                int* __restrict__ boff,
                                                int* __restrict__ bcur, int nb) {
  __shared__ int tmp[1024];
  int t = threadIdx.x;
  int v = (t < nb) ? bcnt[t] : 0;
  tmp[t] = v;
  __syncthreads();
  #pragma unroll
  for (int off = 1; off < 1024; off <<= 1) {
    int x = tmp[t];
    int add = (t >= off) ? tmp[t - off] : 0;
    __syncthreads();
    tmp[t] = x + add;
    __syncthreads();
  }
  if (t < nb) {
    int ex = tmp[t] - v;
    boff[t] = ex;
    bcur[t] = ex;
    if (t == nb - 1) boff[nb] = tmp[t];
  }
}

// block-aggregated scatter (low contention, line-filling writes)
__global__ __launch_bounds__(256) void k_bscat(const int* __restrict__ ei,
                                               int* __restrict__ bcur,
                                               uint2* __restrict__ pairs, int E, int n) {
  __shared__ int lh[1024];
  __shared__ int lc[1024];
  int t = threadIdx.x;
  int tot = E + n;
  int start = blockIdx.x * SCHUNK;
  if (start >= tot) return;
  int end = min(start + SCHUNK, tot);
  for (int k = t; k < 1024; k += 256) { lh[k] = 0; lc[k] = 0; }
  __syncthreads();
  int dreg[SCHUNK / 256];
  #pragma unroll
  for (int q = 0; q < SCHUNK / 256; ++q) {
    int i = start + q * 256 + t;
    int d = (i < end) ? ((i < E) ? ei[E + i] : (i - E)) : -1;
    dreg[q] = d;
    if (d >= 0) atomicAdd(&lh[d >> 7], 1);
  }
  __syncthreads();
  for (int k = t; k < 1024; k += 256) {
    int c = lh[k];
    lh[k] = (c > 0) ? atomicAdd(&bcur[k], c) : 0;
  }
  __syncthreads();
  #pragma unroll
  for (int q = 0; q < SCHUNK / 256; ++q) {
    int i = start + q * 256 + t;
    int d = dreg[q];
    if (d < 0) continue;
    int s = (i < E) ? ei[i] : (i - E);
    int b = d >> 7;
    int loc = atomicAdd(&lc[b], 1);
    pairs[lh[b] + loc] = make_uint2((unsigned)s, (unsigned)d);
  }
}

__global__ __launch_bounds__(256) void k_bfin(const uint2* __restrict__ pairs,
                                              const int* __restrict__ boff,
                                              int* __restrict__ row_off,
                                              int* __restrict__ csr_src,
                                              int n, int tot) {
  __shared__ int ldeg[128];
  __shared__ int lcur[128];
  int b = blockIdx.x;
  int t = threadIdx.x;
  int pb = boff[b], pe = boff[b + 1];
  if (t < 128) ldeg[t] = 0;
  __syncthreads();
  for (int j = pb + t; j < pe; j += 256)
    atomicAdd(&ldeg[pairs[j].y & 127], 1);
  __syncthreads();
  int cnt = (t < 128) ? ldeg[t] : 0;
  for (int off = 1; off < 128; off <<= 1) {
    int add = (t < 128 && t >= off) ? ldeg[t - off] : 0;
    __syncthreads();
    if (t < 128) ldeg[t] += add;
    __syncthreads();
  }
  if (t < 128) {
    int base = pb + ldeg[t] - cnt;
    lcur[t] = base;
    int idx = (b << 7) + t;
    if (idx < n) row_off[idx] = base;
  }
  if (b == 0 && t == 255) row_off[n] = tot;
  __syncthreads();
  for (int j = pb + t; j < pe; j += 256) {
    uint2 pr = pairs[j];
    int pos = atomicAdd(&lcur[pr.y & 127], 1);
    csr_src[pos] = (int)pr.x;
  }
}

// ============ GEMM: [n,K] fp32 @ [K,128] fp32 -> [n,128] bf16 ============
template<int K>
__global__ __launch_bounds__(256) void k_gemm(const float* __restrict__ X,
                                              const float* __restrict__ W,
                                              __hip_bfloat16* __restrict__ Y, int n) {
  __shared__ float Xt[K][36];
  int t = threadIdx.x;
  int r0 = blockIdx.x * 32;
  for (int i = t; i < 32 * K; i += 256) {
    int r = i / K, k = i - r * K;
    int gr = r0 + r;
    Xt[k][r] = (gr < n) ? X[gr * K + k] : 0.f;
  }
  __syncthreads();
  int c  = t & 127;
  int rb = (t >> 7) * 16;
  float acc[16] = {};
  for (int k = 0; k < K; ++k) {
    float w = W[k * 128 + c];
    const float* xr = &Xt[k][rb];
    float4 x0 = *(const float4*)(xr);
    float4 x1 = *(const float4*)(xr + 4);
    float4 x2 = *(const float4*)(xr + 8);
    float4 x3 = *(const float4*)(xr + 12);
    acc[0]  += x0.x * w; acc[1]  += x0.y * w; acc[2]  += x0.z * w; acc[3]  += x0.w * w;
    acc[4]  += x1.x * w; acc[5]  += x1.y * w; acc[6]  += x1.z * w; acc[7]  += x1.w * w;
    acc[8]  += x2.x * w; acc[9]  += x2.y * w; acc[10] += x2.z * w; acc[11] += x2.w * w;
    acc[12] += x3.x * w; acc[13] += x3.y * w; acc[14] += x3.z * w; acc[15] += x3.w * w;
  }
  #pragma unroll
  for (int j = 0; j < 16; ++j) {
    int gr = r0 + rb + j;
    if (gr < n) Y[gr * 128 + c] = __float2bfloat16(acc[j]);
  }
}

// ---------------- alpha: wave per node, coalesced bf16 reads ----------------
template<int LOGC>
__global__ __launch_bounds__(256) void k_alpha(const __hip_bfloat16* __restrict__ H,
    const float* __restrict__ a_s, const float* __restrict__ a_d,
    float* __restrict__ AS, float* __restrict__ AD, int n) {
  int wid  = (int)((blockIdx.x * (size_t)blockDim.x + threadIdx.x) >> 6);
  int lane = threadIdx.x & 63;
  if (wid >= n) return;
  constexpr int SEG = 1 << (LOGC - 1);
  constexpr int NH  = HID >> LOGC;
  int c = 2 * lane;
  ushort2 u = *(const ushort2*)((const unsigned short*)H + wid * HID + c);
  float h0 = bf2f(u.x), h1 = bf2f(u.y);
  float s1 = h0 * a_s[c] + h1 * a_s[c + 1];
  float s2 = h0 * a_d[c] + h1 * a_d[c + 1];
  #pragma unroll
  for (int off = 1; off < SEG; off <<= 1) {
    s1 += __shfl_xor(s1, off);
    s2 += __shfl_xor(s2, off);
  }
  if ((lane & (SEG - 1)) == 0) {
    int h = lane / SEG;
    AS[wid * NH + h] = s1;
    AD[wid * NH + h] = s2;
  }
}

// ---- GAT aggregation: HALF-WAVE per dst node, 4 channels/lane (ushort4),
// ---- cooperative no-max softmax, 4-deep load batching; + ELU + LN + residual
template<int LOGC>
__global__ __launch_bounds__(256) void k_agg_post(const __hip_bfloat16* __restrict__ H,
    const int* __restrict__ row_off, const int* __restrict__ csr_src,
    const float* __restrict__ AS, const float* __restrict__ AD,
    const float* __restrict__ bias, const float* __restrict__ RES,
    const float* __restrict__ gamma, const float* __restrict__ beta,
    float* __restrict__ Y, int n, int has_res) {
  int tid = blockIdx.x * 256 + threadIdx.x;
  int wid = tid >> 5;                      // half-wave (32 lanes) per node
  int ll  = threadIdx.x & 31;              // lane within the half-wave
  if (wid >= n) return;
  constexpr int NH  = HID >> LOGC;                         // heads
  constexpr int SEG = (LOGC >= 7) ? 32 : (1 << (LOGC - 2)); // lanes per head
  int abslane = threadIdx.x & 63;
  int c = ll << 2;                         // 4 channels per lane
  int h = c >> LOGC;
  int r = ll & (SEG - 1);                  // edge slot within head group
  int sbase = abslane & ~(SEG - 1);        // shfl base (same node, same head)
  float adv = AD[wid * NH + h];
  int jb = row_off[wid], je = row_off[wid + 1];
  float den = 0.f, a0 = 0.f, a1 = 0.f, a2 = 0.f, a3 = 0.f;
  const unsigned short* Hu = (const unsigned short*)H;
  for (int j0 = jb; j0 < je; j0 += SEG) {
    int cnt = min(SEG, je - j0);
    int s_l = 0; float p_l = 0.f;
    if (r < cnt) {
      s_l = csr_src[j0 + r];
      float e = AS[s_l * NH + h] + adv;
      e = (e > 0.f) ? e : 0.2f * e;        // leaky_relu(0.2)
      p_l = __expf(e);                     // |e| small by construction
    }
    int k = 0;
    for (; k + 4 <= cnt; k += 4) {
      int sk0 = __shfl(s_l, sbase | k);
      int sk1 = __shfl(s_l, sbase | (k + 1));
      int sk2 = __shfl(s_l, sbase | (k + 2));
      int sk3 = __shfl(s_l, sbase | (k + 3));
      ushort4 u0 = *(const ushort4*)(Hu + (sk0 << 7) + c);
      ushort4 u1 = *(const ushort4*)(Hu + (sk1 << 7) + c);
      ushort4 u2 = *(const ushort4*)(Hu + (sk2 << 7) + c);
      ushort4 u3 = *(const ushort4*)(Hu + (sk3 << 7) + c);
      float p0 = __shfl(p_l, sbase | k);
      float p1 = __shfl(p_l, sbase | (k + 1));
      float p2 = __shfl(p_l, sbase | (k + 2));
      float p3 = __shfl(p_l, sbase | (k + 3));
      den += (p0 + p1) + (p2 + p3);
      a0 = fmaf(p0, bf2f(u0.x), a0); a1 = fmaf(p0, bf2f(u0.y), a1);
      a2 = fmaf(p0, bf2f(u0.z), a2); a3 = fmaf(p0, bf2f(u0.w), a3);
      a0 = fmaf(p1, bf2f(u1.x), a0); a1 = fmaf(p1, bf2f(u1.y), a1);
      a2 = fmaf(p1, bf2f(u1.z), a2); a3 = fmaf(p1, bf2f(u1.w), a3);
      a0 = fmaf(p2, bf2f(u2.x), a0); a1 = fmaf(p2, bf2f(u2.y), a1);
      a2 = fmaf(p2, bf2f(u2.z), a2); a3 = fmaf(p2, bf2f(u2.w), a3);
      a0 = fmaf(p3, bf2f(u3.x), a0); a1 = fmaf(p3, bf2f(u3.y), a1);
      a2 = fmaf(p3, bf2f(u3.z), a2); a3 = fmaf(p3, bf2f(u3.w), a3);
    }
    for (; k < cnt; ++k) {
      int   s  = __shfl(s_l, sbase | k);
      float pk = __shfl(p_l, sbase | k);
      ushort4 u = *(const ushort4*)(Hu + (s << 7) + c);
      den += pk;
      a0 = fmaf(pk, bf2f(u.x), a0); a1 = fmaf(pk, bf2f(u.y), a1);
      a2 = fmaf(pk, bf2f(u.z), a2); a3 = fmaf(pk, bf2f(u.w), a3);
    }
  }
  float inv = 1.f / (den + 1e-16f);
  float4 bv = *(const float4*)(bias + c);
  float t0 = a0 * inv + bv.x;
  float t1 = a1 * inv + bv.y;
  float t2 = a2 * inv + bv.z;
  float t3 = a3 * inv + bv.w;
  float e0 = t0 > 0.f ? t0 : __expf(t0) - 1.f;   // ELU
  float e1 = t1 > 0.f ? t1 : __expf(t1) - 1.f;
  float e2 = t2 > 0.f ? t2 : __expf(t2) - 1.f;
  float e3 = t3 > 0.f ? t3 : __expf(t3) - 1.f;
  float s1 = (e0 + e1) + (e2 + e3);
  float s2 = (e0 * e0 + e1 * e1) + (e2 * e2 + e3 * e3);
  #pragma unroll
  for (int off = 16; off >= 1; off >>= 1) {      // reduce within half-wave
    s1 += __shfl_xor(s1, off);
    s2 += __shfl_xor(s2, off);
  }
  float mu  = s1 * (1.f / 128.f);
  float var = s2 * (1.f / 128.f) - mu * mu;
  float rs  = rsqrtf(var + 1e-5f);
  int base = wid * HID;
  float4 rv = make_float4(0.f, 0.f, 0.f, 0.f);
  if (has_res) rv = *(const float4*)(RES + base + c);
  float4 gv = *(const float4*)(gamma + c);
  float4 betv = *(const float4*)(beta + c);
  float4 o;
  o.x = (e0 - mu) * rs * gv.x + betv.x + rv.x;
  o.y = (e1 - mu) * rs * gv.y + betv.y + rv.y;
  o.z = (e2 - mu) * rs * gv.z + betv.z + rv.z;
  o.w = (e3 - mu) * rs * gv.w + betv.w + rv.w;
  *(float4*)(Y + base + c) = o;
}

// ---------------- global mean pool: wave per graph (batch is sorted) ----------------
__global__ __launch_bounds__(256) void k_pool_seg(const float* __restrict__ Hf,
    const int* __restrict__ batch, float* __restrict__ pool, int n, int G) {
  int wid  = (int)((blockIdx.x * (size_t)blockDim.x + threadIdx.x) >> 6);
  int lane = threadIdx.x & 63;
  if (wid >= G) return;
  int lo = 0, hi = n;
  while (lo < hi) { int mid = (lo + hi) >> 1; if (batch[mid] < wid) lo = mid + 1; else hi = mid; }
  int start = lo;
  hi = n;
  while (lo < hi) { int mid = (lo + hi) >> 1; if (batch[mid] < wid + 1) lo = mid + 1; else hi = mid; }
  int end = lo;
  int c = 2 * lane;
  float s0 = 0.f, s1 = 0.f;
  for (int i = start; i < end; ++i) {
    float2 v = *(const float2*)(Hf + (size_t)i * HID + c);
    s0 += v.x; s1 += v.y;
  }
  float inv = 1.f / (float)max(end - start, 1);
  pool[(size_t)wid * HID + c]     = s0 * inv;
  pool[(size_t)wid * HID + c + 1] = s1 * inv;
}

// ---------------- small MLP: [rows,128] @ [128,128] + b (opt ELU) ----------------
__global__ void k_mlp(const float* __restrict__ X, const float* __restrict__ Wt,
                      const float* __restrict__ bb, float* __restrict__ Y,
                      int rows, int do_elu) {
  int i = blockIdx.x * blockDim.x + threadIdx.x;
  if (i >= rows * HID) return;
  int r = i >> 7, c = i & 127;
  const float* xr = X + (size_t)r * HID;
  float acc = bb[c];
  for (int k = 0; k < HID; ++k) acc += xr[k] * Wt[k * HID + c];
  if (do_elu) acc = acc > 0.f ? acc : __expf(acc) - 1.f;
  Y[i] = acc;
}

extern "C" void kernel_launch(void* const* d_in, const int* in_sizes, int n_in,
                              void* d_out, int out_size, void* d_ws, size_t ws_size,
                              hipStream_t stream) {
  const float* x   = (const float*)d_in[0];
  const int*   ei  = (const int*)d_in[1];
  const int*   bat = (const int*)d_in[2];
  const float* W1  = (const float*)d_in[3];
  const float* as1 = (const float*)d_in[4];
  const float* ad1 = (const float*)d_in[5];
  const float* b1  = (const float*)d_in[6];
  const float* W2  = (const float*)d_in[7];
  const float* as2 = (const float*)d_in[8];
  const float* ad2 = (const float*)d_in[9];
  const float* b2  = (const float*)d_in[10];
  const float* W3  = (const float*)d_in[11];
  const float* as3 = (const float*)d_in[12];
  const float* ad3 = (const float*)d_in[13];
  const float* b3  = (const float*)d_in[14];
  const float* g1  = (const float*)d_in[15];
  const float* be1 = (const float*)d_in[16];
  const float* g2  = (const float*)d_in[17];
  const float* be2 = (const float*)d_in[18];
  const float* g3  = (const float*)d_in[19];
  const float* be3 = (const float*)d_in[20];
  const float* lw1 = (const float*)d_in[21];
  const float* lb1 = (const float*)d_in[22];
  const float* lw2 = (const float*)d_in[23];
  const float* lb2 = (const float*)d_in[24];

  int N = in_sizes[0] / F_IN;
  int E = in_sizes[1] / 2;
  int G = out_size / HID;
  int tot = E + N;
  int nb  = (N + 127) >> 7;          // buckets (<=1024)

  char* p = (char*)d_ws;
  auto alloc = [&](size_t bytes) { char* r = p; p += (bytes + 511) & ~(size_t)511; return r; };
  int*   bcnt    = (int*)  alloc(1024 * 4);
  int*   boff    = (int*)  alloc(1025 * 4);
  int*   bcur    = (int*)  alloc(1024 * 4);
  int*   row_off = (int*)  alloc((size_t)(N + 1) * 4);
  int*   csr_src = (int*)  alloc((size_t)tot * 4);
  uint2* pairs   = (uint2*)alloc((size_t)tot * 8);
  float* AS      = (float*)alloc((size_t)N * 8 * 4);
  float* AD      = (float*)alloc((size_t)N * 8 * 4);
  __hip_bfloat16* Hb = (__hip_bfloat16*)alloc((size_t)N * HID * 2);
  float* F0      = (float*)alloc((size_t)N * HID * 4);
  float* F1      = (float*)alloc((size_t)N * HID * 4);
  float* pool    = (float*)alloc((size_t)G * HID * 4);
  float* t1      = (float*)alloc((size_t)G * HID * 4);

  hipMemsetAsync(bcnt, 0, 1024 * 4, stream);

  int sb = (tot + SCHUNK - 1) / SCHUNK;
  k_bhist<<<256, 256, 0, stream>>>(ei, bcnt, E, N);
  k_bscan<<<1, 1024, 0, stream>>>(bcnt, boff, bcur, nb);
  k_bscat<<<sb, 256, 0, stream>>>(ei, bcur, pairs, E, N);
  k_bfin <<<nb, 256, 0, stream>>>(pairs, boff, row_off, csr_src, N, tot);

  int gb  = (N + 31) / 32;                // GEMM blocks (32 rows each)
  int nw  = (N + 3) / 4;                  // wave-per-node kernels
  int nh2 = (N + 7) / 8;                  // half-wave-per-node agg: 8 nodes/block

  // ---- layer 1: x[N,64] -> Hb -> agg+post -> F0
  k_gemm<64><<<gb, 256, 0, stream>>>(x, W1, Hb, N);
  k_alpha<4><<<nw, 256, 0, stream>>>(Hb, as1, ad1, AS, AD, N);
  k_agg_post<4><<<nh2, 256, 0, stream>>>(Hb, row_off, csr_src, AS, AD, b1,
                                         nullptr, g1, be1, F0, N, 0);

  // ---- layer 2: F0 -> Hb -> agg+post(+F0) -> F1
  k_gemm<128><<<gb, 256, 0, stream>>>(F0, W2, Hb, N);
  k_alpha<7><<<nw, 256, 0, stream>>>(Hb, as2, ad2, AS, AD, N);
  k_agg_post<7><<<nh2, 256, 0, stream>>>(Hb, row_off, csr_src, AS, AD, b2,
                                         F0, g2, be2, F1, N, 1);

  // ---- layer 3: F1 -> Hb -> agg+post(+F1) -> F0
  k_gemm<128><<<gb, 256, 0, stream>>>(F1, W3, Hb, N);
  k_alpha<7><<<nw, 256, 0, stream>>>(Hb, as3, ad3, AS, AD, N);
  k_agg_post<7><<<nh2, 256, 0, stream>>>(Hb, row_off, csr_src, AS, AD, b3,
                                         F1, g3, be3, F0, N, 1);

  // ---- pool + MLP head
  k_pool_seg<<<(G + 3) / 4, 256, 0, stream>>>(F0, bat, pool, N, G);
  k_mlp<<<(G * HID + 255) / 256, 256, 0, stream>>>(pool, lw1, lb1, t1, G, 1);
  k_mlp<<<(G * HID + 255) / 256, 256, 0, stream>>>(t1, lw2, lb2, (float*)d_out, G, 0);
}

// Round 8
// 468.369 us; speedup vs baseline: 2.3938x; 1.1826x over previous
//
#include <hip/hip_runtime.h>
#include <hip/hip_bf16.h>
#include <cstdint>
#include <cstddef>

constexpr int F_IN = 64;
constexpr int HID  = 128;
constexpr int SCHUNK = 4096;   // edges per scatter block (16/thread)

typedef __attribute__((ext_vector_type(8))) short short8v;
typedef __attribute__((ext_vector_type(4))) float f32x4;

__device__ __forceinline__ float bf2f(unsigned short u) {
  return __uint_as_float((unsigned)u << 16);
}
__device__ __forceinline__ unsigned short f2bf(float x) {
  unsigned u = __float_as_uint(x);
  u += 0x7FFFu + ((u >> 16) & 1u);   // round-to-nearest-even
  return (unsigned short)(u >> 16);
}

// ================= CSR build via 1024-way bucketing =================
__global__ __launch_bounds__(256) void k_bhist(const int* __restrict__ ei,
                                               int* __restrict__ bcnt, int E, int n) {
  __shared__ int hist[1024];
  int t = threadIdx.x;
  for (int k = t; k < 1024; k += 256) hist[k] = 0;
  __syncthreads();
  int tot = E + n;
  for (int i = blockIdx.x * 256 + t; i < tot; i += gridDim.x * 256) {
    int d = (i < E) ? ei[E + i] : (i - E);
    atomicAdd(&hist[d >> 7], 1);
  }
  __syncthreads();
  for (int k = t; k < 1024; k += 256)
    if (hist[k]) atomicAdd(&bcnt[k], hist[k]);
}

__global__ __launch_bounds__(1024) void k_bscan(const int* __restrict__ bcnt,
                                                int* __restrict__ boff,
                                                int* __restrict__ bcur, int nb) {
  __shared__ int tmp[1024];
  int t = threadIdx.x;
  int v = (t < nb) ? bcnt[t] : 0;
  tmp[t] = v;
  __syncthreads();
  #pragma unroll
  for (int off = 1; off < 1024; off <<= 1) {
    int x = tmp[t];
    int add = (t >= off) ? tmp[t - off] : 0;
    __syncthreads();
    tmp[t] = x + add;
    __syncthreads();
  }
  if (t < nb) {
    int ex = tmp[t] - v;
    boff[t] = ex;
    bcur[t] = ex;
    if (t == nb - 1) boff[nb] = tmp[t];
  }
}

__global__ __launch_bounds__(256) void k_bscat(const int* __restrict__ ei,
                                               int* __restrict__ bcur,
                                               uint2* __restrict__ pairs, int E, int n) {
  __shared__ int lh[1024];
  __shared__ int lc[1024];
  int t = threadIdx.x;
  int tot = E + n;
  int start = blockIdx.x * SCHUNK;
  if (start >= tot) return;
  int end = min(start + SCHUNK, tot);
  for (int k = t; k < 1024; k += 256) { lh[k] = 0; lc[k] = 0; }
  __syncthreads();
  int dreg[SCHUNK / 256];
  #pragma unroll
  for (int q = 0; q < SCHUNK / 256; ++q) {
    int i = start + q * 256 + t;
    int d = (i < end) ? ((i < E) ? ei[E + i] : (i - E)) : -1;
    dreg[q] = d;
    if (d >= 0) atomicAdd(&lh[d >> 7], 1);
  }
  __syncthreads();
  for (int k = t; k < 1024; k += 256) {
    int c = lh[k];
    lh[k] = (c > 0) ? atomicAdd(&bcur[k], c) : 0;
  }
  __syncthreads();
  #pragma unroll
  for (int q = 0; q < SCHUNK / 256; ++q) {
    int i = start + q * 256 + t;
    int d = dreg[q];
    if (d < 0) continue;
    int s = (i < E) ? ei[i] : (i - E);
    int b = d >> 7;
    int loc = atomicAdd(&lc[b], 1);
    pairs[lh[b] + loc] = make_uint2((unsigned)s, (unsigned)d);
  }
}

__global__ __launch_bounds__(256) void k_bfin(const uint2* __restrict__ pairs,
                                              const int* __restrict__ boff,
                                              int* __restrict__ row_off,
                                              int* __restrict__ csr_src,
                                              int n, int tot) {
  __shared__ int ldeg[128];
  __shared__ int lcur[128];
  int b = blockIdx.x;
  int t = threadIdx.x;
  int pb = boff[b], pe = boff[b + 1];
  if (t < 128) ldeg[t] = 0;
  __syncthreads();
  for (int j = pb + t; j < pe; j += 256)
    atomicAdd(&ldeg[pairs[j].y & 127], 1);
  __syncthreads();
  int cnt = (t < 128) ? ldeg[t] : 0;
  for (int off = 1; off < 128; off <<= 1) {
    int add = (t < 128 && t >= off) ? ldeg[t - off] : 0;
    __syncthreads();
    if (t < 128) ldeg[t] += add;
    __syncthreads();
  }
  if (t < 128) {
    int base = pb + ldeg[t] - cnt;
    lcur[t] = base;
    int idx = (b << 7) + t;
    if (idx < n) row_off[idx] = base;
  }
  if (b == 0 && t == 255) row_off[n] = tot;
  __syncthreads();
  for (int j = pb + t; j < pe; j += 256) {
    uint2 pr = pairs[j];
    int pos = atomicAdd(&lcur[pr.y & 127], 1);
    csr_src[pos] = (int)pr.x;
  }
}

// ---------------- fp32 -> bf16 convert ----------------
__global__ void k_tobf(const float* __restrict__ X, unsigned short* __restrict__ Y,
                       int total) {
  int i = blockIdx.x * 256 + threadIdx.x;
  if (i < total) Y[i] = f2bf(X[i]);
}

// ---- pack W [K,128] fp32 into MFMA B-fragment order, bf16 ----
// Wf[((ks*8 + t)*64 + lane)*8 + j] = W[(ks*32 + (lane>>4)*8 + j)*128 + t*16 + (lane&15)]
__global__ void k_wpack(const float* __restrict__ W, unsigned short* __restrict__ Wf,
                        int K) {
  int i = blockIdx.x * 256 + threadIdx.x;
  int total = (K >> 5) * 4096;
  if (i >= total) return;
  int j    = i & 7;
  int lane = (i >> 3) & 63;
  int t    = (i >> 9) & 7;
  int ks   = i >> 12;
  int k = ks * 32 + (lane >> 4) * 8 + j;
  int c = t * 16 + (lane & 15);
  Wf[i] = f2bf(W[k * 128 + c]);
}

// ============ MFMA GEMM: [n,K] bf16 @ packed Wf -> [n,128] bf16 ============
// block = 256 (4 waves), wave computes 16 rows x 128 cols
template<int K>
__global__ __launch_bounds__(256) void k_mgemm(const short* __restrict__ Xb,
                                               const short* __restrict__ Wf,
                                               unsigned short* __restrict__ Y, int n) {
  int wv   = threadIdx.x >> 6;
  int lane = threadIdx.x & 63;
  int r0   = blockIdx.x * 64 + wv * 16;
  int ln = lane & 15, kg = lane >> 4;
  f32x4 acc[8] = {};
  int arow = min(r0 + ln, n - 1);
  const short* aptr = Xb + arow * K + kg * 8;
  #pragma unroll
  for (int ks = 0; ks < K / 32; ++ks) {
    short8v a = *(const short8v*)(aptr + ks * 32);
    const short* wp = Wf + ks * 4096 + lane * 8;
    #pragma unroll
    for (int t = 0; t < 8; ++t) {
      short8v b = *(const short8v*)(wp + t * 512);
      acc[t] = __builtin_amdgcn_mfma_f32_16x16x32_bf16(a, b, acc[t], 0, 0, 0);
    }
  }
  #pragma unroll
  for (int t = 0; t < 8; ++t) {
    #pragma unroll
    for (int reg = 0; reg < 4; ++reg) {
      int r = r0 + kg * 4 + reg;          // C row = (lane>>4)*4 + reg
      if (r < n) Y[r * 128 + t * 16 + ln] = f2bf(acc[t][reg]);
    }
  }
}

// ---------------- alpha: wave per node, coalesced bf16 reads ----------------
template<int LOGC>
__global__ __launch_bounds__(256) void k_alpha(const unsigned short* __restrict__ H,
    const float* __restrict__ a_s, const float* __restrict__ a_d,
    float* __restrict__ AS, float* __restrict__ AD, int n) {
  int wid  = (int)((blockIdx.x * (size_t)blockDim.x + threadIdx.x) >> 6);
  int lane = threadIdx.x & 63;
  if (wid >= n) return;
  constexpr int SEG = 1 << (LOGC - 1);
  constexpr int NH  = HID >> LOGC;
  int c = 2 * lane;
  ushort2 u = *(const ushort2*)(H + wid * HID + c);
  float h0 = bf2f(u.x), h1 = bf2f(u.y);
  float s1 = h0 * a_s[c] + h1 * a_s[c + 1];
  float s2 = h0 * a_d[c] + h1 * a_d[c + 1];
  #pragma unroll
  for (int off = 1; off < SEG; off <<= 1) {
    s1 += __shfl_xor(s1, off);
    s2 += __shfl_xor(s2, off);
  }
  if ((lane & (SEG - 1)) == 0) {
    int h = lane / SEG;
    AS[wid * NH + h] = s1;
    AD[wid * NH + h] = s2;
  }
}

// ---- GAT aggregation: HALF-WAVE per dst node, 4 channels/lane (ushort4),
// ---- cooperative no-max softmax, 4-deep load batching; + ELU + LN + residual
// ---- optionally also emits bf16 copy (next layer's GEMM input)
template<int LOGC>
__global__ __launch_bounds__(256) void k_agg_post(const unsigned short* __restrict__ Hu,
    const int* __restrict__ row_off, const int* __restrict__ csr_src,
    const float* __restrict__ AS, const float* __restrict__ AD,
    const float* __restrict__ bias, const float* __restrict__ RES,
    const float* __restrict__ gamma, const float* __restrict__ beta,
    float* __restrict__ Y, unsigned short* __restrict__ Yb, int n, int has_res) {
  int tid = blockIdx.x * 256 + threadIdx.x;
  int wid = tid >> 5;                      // half-wave (32 lanes) per node
  int ll  = threadIdx.x & 31;
  if (wid >= n) return;
  constexpr int NH  = HID >> LOGC;
  constexpr int SEG = (LOGC >= 7) ? 32 : (1 << (LOGC - 2));
  int abslane = threadIdx.x & 63;
  int c = ll << 2;
  int h = c >> LOGC;
  int r = ll & (SEG - 1);
  int sbase = abslane & ~(SEG - 1);
  float adv = AD[wid * NH + h];
  int jb = row_off[wid], je = row_off[wid + 1];
  float den = 0.f, a0 = 0.f, a1 = 0.f, a2 = 0.f, a3 = 0.f;
  for (int j0 = jb; j0 < je; j0 += SEG) {
    int cnt = min(SEG, je - j0);
    int s_l = 0; float p_l = 0.f;
    if (r < cnt) {
      s_l = csr_src[j0 + r];
      float e = AS[s_l * NH + h] + adv;
      e = (e > 0.f) ? e : 0.2f * e;
      p_l = __expf(e);
    }
    int k = 0;
    for (; k + 4 <= cnt; k += 4) {
      int sk0 = __shfl(s_l, sbase | k);
      int sk1 = __shfl(s_l, sbase | (k + 1));
      int sk2 = __shfl(s_l, sbase | (k + 2));
      int sk3 = __shfl(s_l, sbase | (k + 3));
      ushort4 u0 = *(const ushort4*)(Hu + (sk0 << 7) + c);
      ushort4 u1 = *(const ushort4*)(Hu + (sk1 << 7) + c);
      ushort4 u2 = *(const ushort4*)(Hu + (sk2 << 7) + c);
      ushort4 u3 = *(const ushort4*)(Hu + (sk3 << 7) + c);
      float p0 = __shfl(p_l, sbase | k);
      float p1 = __shfl(p_l, sbase | (k + 1));
      float p2 = __shfl(p_l, sbase | (k + 2));
      float p3 = __shfl(p_l, sbase | (k + 3));
      den += (p0 + p1) + (p2 + p3);
      a0 = fmaf(p0, bf2f(u0.x), a0); a1 = fmaf(p0, bf2f(u0.y), a1);
      a2 = fmaf(p0, bf2f(u0.z), a2); a3 = fmaf(p0, bf2f(u0.w), a3);
      a0 = fmaf(p1, bf2f(u1.x), a0); a1 = fmaf(p1, bf2f(u1.y), a1);
      a2 = fmaf(p1, bf2f(u1.z), a2); a3 = fmaf(p1, bf2f(u1.w), a3);
      a0 = fmaf(p2, bf2f(u2.x), a0); a1 = fmaf(p2, bf2f(u2.y), a1);
      a2 = fmaf(p2, bf2f(u2.z), a2); a3 = fmaf(p2, bf2f(u2.w), a3);
      a0 = fmaf(p3, bf2f(u3.x), a0); a1 = fmaf(p3, bf2f(u3.y), a1);
      a2 = fmaf(p3, bf2f(u3.z), a2); a3 = fmaf(p3, bf2f(u3.w), a3);
    }
    for (; k < cnt; ++k) {
      int   s  = __shfl(s_l, sbase | k);
      float pk = __shfl(p_l, sbase | k);
      ushort4 u = *(const ushort4*)(Hu + (s << 7) + c);
      den += pk;
      a0 = fmaf(pk, bf2f(u.x), a0); a1 = fmaf(pk, bf2f(u.y), a1);
      a2 = fmaf(pk, bf2f(u.z), a2); a3 = fmaf(pk, bf2f(u.w), a3);
    }
  }
  float inv = 1.f / (den + 1e-16f);
  float4 bv = *(const float4*)(bias + c);
  float t0 = a0 * inv + bv.x;
  float t1 = a1 * inv + bv.y;
  float t2 = a2 * inv + bv.z;
  float t3 = a3 * inv + bv.w;
  float e0 = t0 > 0.f ? t0 : __expf(t0) - 1.f;
  float e1 = t1 > 0.f ? t1 : __expf(t1) - 1.f;
  float e2 = t2 > 0.f ? t2 : __expf(t2) - 1.f;
  float e3 = t3 > 0.f ? t3 : __expf(t3) - 1.f;
  float s1 = (e0 + e1) + (e2 + e3);
  float s2 = (e0 * e0 + e1 * e1) + (e2 * e2 + e3 * e3);
  #pragma unroll
  for (int off = 16; off >= 1; off >>= 1) {
    s1 += __shfl_xor(s1, off);
    s2 += __shfl_xor(s2, off);
  }
  float mu  = s1 * (1.f / 128.f);
  float var = s2 * (1.f / 128.f) - mu * mu;
  float rs  = rsqrtf(var + 1e-5f);
  int base = wid * HID;
  float4 rv = make_float4(0.f, 0.f, 0.f, 0.f);
  if (has_res) rv = *(const float4*)(RES + base + c);
  float4 gv = *(const float4*)(gamma + c);
  float4 betv = *(const float4*)(beta + c);
  float4 o;
  o.x = (e0 - mu) * rs * gv.x + betv.x + rv.x;
  o.y = (e1 - mu) * rs * gv.y + betv.y + rv.y;
  o.z = (e2 - mu) * rs * gv.z + betv.z + rv.z;
  o.w = (e3 - mu) * rs * gv.w + betv.w + rv.w;
  *(float4*)(Y + base + c) = o;
  if (Yb) {
    ushort4 ob;
    ob.x = f2bf(o.x);
    ob.y = f2bf(o.y);
    ob.z = f2bf(o.z);
    ob.w = f2bf(o.w);
    *(ushort4*)(Yb + base + c) = ob;
  }
}

// ---------------- global mean pool: wave per graph (batch is sorted) ----------------
__global__ __launch_bounds__(256) void k_pool_seg(const float* __restrict__ Hf,
    const int* __restrict__ batch, float* __restrict__ pool, int n, int G) {
  int wid  = (int)((blockIdx.x * (size_t)blockDim.x + threadIdx.x) >> 6);
  int lane = threadIdx.x & 63;
  if (wid >= G) return;
  int lo = 0, hi = n;
  while (lo < hi) { int mid = (lo + hi) >> 1; if (batch[mid] < wid) lo = mid + 1; else hi = mid; }
  int start = lo;
  hi = n;
  while (lo < hi) { int mid = (lo + hi) >> 1; if (batch[mid] < wid + 1) lo = mid + 1; else hi = mid; }
  int end = lo;
  int c = 2 * lane;
  float s0 = 0.f, s1 = 0.f;
  for (int i = start; i < end; ++i) {
    float2 v = *(const float2*)(Hf + (size_t)i * HID + c);
    s0 += v.x; s1 += v.y;
  }
  float inv = 1.f / (float)max(end - start, 1);
  pool[(size_t)wid * HID + c]     = s0 * inv;
  pool[(size_t)wid * HID + c + 1] = s1 * inv;
}

// ---------------- small MLP: [rows,128] @ [128,128] + b (opt ELU) ----------------
__global__ void k_mlp(const float* __restrict__ X, const float* __restrict__ Wt,
                      const float* __restrict__ bb, float* __restrict__ Y,
                      int rows, int do_elu) {
  int i = blockIdx.x * blockDim.x + threadIdx.x;
  if (i >= rows * HID) return;
  int r = i >> 7, c = i & 127;
  const float* xr = X + (size_t)r * HID;
  float acc = bb[c];
  for (int k = 0; k < HID; ++k) acc += xr[k] * Wt[k * HID + c];
  if (do_elu) acc = acc > 0.f ? acc : __expf(acc) - 1.f;
  Y[i] = acc;
}

extern "C" void kernel_launch(void* const* d_in, const int* in_sizes, int n_in,
                              void* d_out, int out_size, void* d_ws, size_t ws_size,
                              hipStream_t stream) {
  const float* x   = (const float*)d_in[0];
  const int*   ei  = (const int*)d_in[1];
  const int*   bat = (const int*)d_in[2];
  const float* W1  = (const float*)d_in[3];
  const float* as1 = (const float*)d_in[4];
  const float* ad1 = (const float*)d_in[5];
  const float* b1  = (const float*)d_in[6];
  const float* W2  = (const float*)d_in[7];
  const float* as2 = (const float*)d_in[8];
  const float* ad2 = (const float*)d_in[9];
  const float* b2  = (const float*)d_in[10];
  const float* W3  = (const float*)d_in[11];
  const float* as3 = (const float*)d_in[12];
  const float* ad3 = (const float*)d_in[13];
  const float* b3  = (const float*)d_in[14];
  const float* g1  = (const float*)d_in[15];
  const float* be1 = (const float*)d_in[16];
  const float* g2  = (const float*)d_in[17];
  const float* be2 = (const float*)d_in[18];
  const float* g3  = (const float*)d_in[19];
  const float* be3 = (const float*)d_in[20];
  const float* lw1 = (const float*)d_in[21];
  const float* lb1 = (const float*)d_in[22];
  const float* lw2 = (const float*)d_in[23];
  const float* lb2 = (const float*)d_in[24];

  int N = in_sizes[0] / F_IN;
  int E = in_sizes[1] / 2;
  int G = out_size / HID;
  int tot = E + N;
  int nb  = (N + 127) >> 7;          // buckets (<=1024)

  char* p = (char*)d_ws;
  auto alloc = [&](size_t bytes) { char* r = p; p += (bytes + 511) & ~(size_t)511; return r; };
  int*   bcnt    = (int*)  alloc(1024 * 4);
  int*   boff    = (int*)  alloc(1025 * 4);
  int*   bcur    = (int*)  alloc(1024 * 4);
  int*   row_off = (int*)  alloc((size_t)(N + 1) * 4);
  int*   csr_src = (int*)  alloc((size_t)tot * 4);
  uint2* pairs   = (uint2*)alloc((size_t)tot * 8);    // dead after k_bfin
  float* AS      = (float*)alloc((size_t)N * 8 * 4);
  float* AD      = (float*)alloc((size_t)N * 8 * 4);
  unsigned short* Hb  = (unsigned short*)alloc((size_t)N * HID * 2);
  unsigned short* Fb  = (unsigned short*)alloc((size_t)N * HID * 2);
  float* F0      = (float*)alloc((size_t)N * HID * 4);
  float* F1      = (float*)alloc((size_t)N * HID * 4);
  float* pool    = (float*)alloc((size_t)G * HID * 4);
  float* t1      = (float*)alloc((size_t)G * HID * 4);
  unsigned short* Wf1 = (unsigned short*)alloc(64 * 128 * 2);
  unsigned short* Wf2 = (unsigned short*)alloc(128 * 128 * 2);
  unsigned short* Wf3 = (unsigned short*)alloc(128 * 128 * 2);
  unsigned short* xb  = (unsigned short*)pairs;       // alias dead pairs buffer

  (void)hipMemsetAsync(bcnt, 0, 1024 * 4, stream);

  int sb = (tot + SCHUNK - 1) / SCHUNK;
  k_bhist<<<256, 256, 0, stream>>>(ei, bcnt, E, N);
  k_bscan<<<1, 1024, 0, stream>>>(bcnt, boff, bcur, nb);
  k_bscat<<<sb, 256, 0, stream>>>(ei, bcur, pairs, E, N);
  k_bfin <<<nb, 256, 0, stream>>>(pairs, boff, row_off, csr_src, N, tot);

  // prep for MFMA gemms (pairs is dead now; xb aliases it)
  k_tobf <<<(N * F_IN + 255) / 256, 256, 0, stream>>>(x, xb, N * F_IN);
  k_wpack<<<(64 * 128 + 255) / 256, 256, 0, stream>>>(W1, Wf1, 64);
  k_wpack<<<(128 * 128 + 255) / 256, 256, 0, stream>>>(W2, Wf2, 128);
  k_wpack<<<(128 * 128 + 255) / 256, 256, 0, stream>>>(W3, Wf3, 128);

  int mb  = (N + 63) / 64;                // MFMA GEMM blocks (64 rows each)
  int nw  = (N + 3) / 4;                  // wave-per-node kernels
  int nh2 = (N + 7) / 8;                  // half-wave-per-node agg

  // ---- layer 1: xb[N,64] -> Hb -> agg+post -> F0 (+Fb)
  k_mgemm<64><<<mb, 256, 0, stream>>>((const short*)xb, (const short*)Wf1, Hb, N);
  k_alpha<4><<<nw, 256, 0, stream>>>(Hb, as1, ad1, AS, AD, N);
  k_agg_post<4><<<nh2, 256, 0, stream>>>(Hb, row_off, csr_src, AS, AD, b1,
                                         nullptr, g1, be1, F0, Fb, N, 0);

  // ---- layer 2: Fb -> Hb -> agg+post(+F0) -> F1 (+Fb)
  k_mgemm<128><<<mb, 256, 0, stream>>>((const short*)Fb, (const short*)Wf2, Hb, N);
  k_alpha<7><<<nw, 256, 0, stream>>>(Hb, as2, ad2, AS, AD, N);
  k_agg_post<7><<<nh2, 256, 0, stream>>>(Hb, row_off, csr_src, AS, AD, b2,
                                         F0, g2, be2, F1, Fb, N, 1);

  // ---- layer 3: Fb -> Hb -> agg+post(+F1) -> F0
  k_mgemm<128><<<mb, 256, 0, stream>>>((const short*)Fb, (const short*)Wf3, Hb, N);
  k_alpha<7><<<nw, 256, 0, stream>>>(Hb, as3, ad3, AS, AD, N);
  k_agg_post<7><<<nh2, 256, 0, stream>>>(Hb, row_off, csr_src, AS, AD, b3,
                                         F1, g3, be3, F0, nullptr, N, 1);

  // ---- pool + MLP head
  k_pool_seg<<<(G + 3) / 4, 256, 0, stream>>>(F0, bat, pool, N, G);
  k_mlp<<<(G * HID + 255) / 256, 256, 0, stream>>>(pool, lw1, lb1, t1, G, 1);
  k_mlp<<<(G * HID + 255) / 256, 256, 0, stream>>>(t1, lw2, lb2, (float*)d_out, G, 0);
}

// Round 9
// 419.979 us; speedup vs baseline: 2.6696x; 1.1152x over previous
//
#include <hip/hip_runtime.h>
#include <hip/hip_bf16.h>
#include <cstdint>
#include <cstddef>

constexpr int F_IN = 64;
constexpr int HID  = 128;
constexpr int SCHUNK = 4096;   // edges per scatter block (16/thread)

typedef __attribute__((ext_vector_type(8))) short short8v;
typedef __attribute__((ext_vector_type(4))) float f32x4;

__device__ __forceinline__ float bf2f(unsigned short u) {
  return __uint_as_float((unsigned)u << 16);
}
__device__ __forceinline__ unsigned short f2bf(float x) {
  unsigned u = __float_as_uint(x);
  u += 0x7FFFu + ((u >> 16) & 1u);   // round-to-nearest-even
  return (unsigned short)(u >> 16);
}

// ================= CSR build via 1024-way bucketing =================
__global__ __launch_bounds__(256) void k_bhist(const int* __restrict__ ei,
                                               int* __restrict__ bcnt, int E, int n) {
  __shared__ int hist[1024];
  int t = threadIdx.x;
  for (int k = t; k < 1024; k += 256) hist[k] = 0;
  __syncthreads();
  int tot = E + n;
  for (int i = blockIdx.x * 256 + t; i < tot; i += gridDim.x * 256) {
    int d = (i < E) ? ei[E + i] : (i - E);
    atomicAdd(&hist[d >> 7], 1);
  }
  __syncthreads();
  for (int k = t; k < 1024; k += 256)
    if (hist[k]) atomicAdd(&bcnt[k], hist[k]);
}

__global__ __launch_bounds__(1024) void k_bscan(const int* __restrict__ bcnt,
                                                int* __restrict__ boff,
                                                int* __restrict__ bcur, int nb) {
  __shared__ int tmp[1024];
  int t = threadIdx.x;
  int v = (t < nb) ? bcnt[t] : 0;
  tmp[t] = v;
  __syncthreads();
  #pragma unroll
  for (int off = 1; off < 1024; off <<= 1) {
    int x = tmp[t];
    int add = (t >= off) ? tmp[t - off] : 0;
    __syncthreads();
    tmp[t] = x + add;
    __syncthreads();
  }
  if (t < nb) {
    int ex = tmp[t] - v;
    boff[t] = ex;
    bcur[t] = ex;
    if (t == nb - 1) boff[nb] = tmp[t];
  }
}

__global__ __launch_bounds__(256) void k_bscat(const int* __restrict__ ei,
                                               int* __restrict__ bcur,
                                               uint2* __restrict__ pairs, int E, int n) {
  __shared__ int lh[1024];
  __shared__ int lc[1024];
  int t = threadIdx.x;
  int tot = E + n;
  int start = blockIdx.x * SCHUNK;
  if (start >= tot) return;
  int end = min(start + SCHUNK, tot);
  for (int k = t; k < 1024; k += 256) { lh[k] = 0; lc[k] = 0; }
  __syncthreads();
  int dreg[SCHUNK / 256];
  #pragma unroll
  for (int q = 0; q < SCHUNK / 256; ++q) {
    int i = start + q * 256 + t;
    int d = (i < end) ? ((i < E) ? ei[E + i] : (i - E)) : -1;
    dreg[q] = d;
    if (d >= 0) atomicAdd(&lh[d >> 7], 1);
  }
  __syncthreads();
  for (int k = t; k < 1024; k += 256) {
    int c = lh[k];
    lh[k] = (c > 0) ? atomicAdd(&bcur[k], c) : 0;
  }
  __syncthreads();
  #pragma unroll
  for (int q = 0; q < SCHUNK / 256; ++q) {
    int i = start + q * 256 + t;
    int d = dreg[q];
    if (d < 0) continue;
    int s = (i < E) ? ei[i] : (i - E);
    int b = d >> 7;
    int loc = atomicAdd(&lc[b], 1);
    pairs[lh[b] + loc] = make_uint2((unsigned)s, (unsigned)d);
  }
}

__global__ __launch_bounds__(256) void k_bfin(const uint2* __restrict__ pairs,
                                              const int* __restrict__ boff,
                                              int* __restrict__ row_off,
                                              int* __restrict__ csr_src,
                                              int n, int tot) {
  __shared__ int ldeg[128];
  __shared__ int lcur[128];
  int b = blockIdx.x;
  int t = threadIdx.x;
  int pb = boff[b], pe = boff[b + 1];
  if (t < 128) ldeg[t] = 0;
  __syncthreads();
  for (int j = pb + t; j < pe; j += 256)
    atomicAdd(&ldeg[pairs[j].y & 127], 1);
  __syncthreads();
  int cnt = (t < 128) ? ldeg[t] : 0;
  for (int off = 1; off < 128; off <<= 1) {
    int add = (t < 128 && t >= off) ? ldeg[t - off] : 0;
    __syncthreads();
    if (t < 128) ldeg[t] += add;
    __syncthreads();
  }
  if (t < 128) {
    int base = pb + ldeg[t] - cnt;
    lcur[t] = base;
    int idx = (b << 7) + t;
    if (idx < n) row_off[idx] = base;
  }
  if (b == 0 && t == 255) row_off[n] = tot;
  __syncthreads();
  for (int j = pb + t; j < pe; j += 256) {
    uint2 pr = pairs[j];
    int pos = atomicAdd(&lcur[pr.y & 127], 1);
    csr_src[pos] = (int)pr.x;
  }
}

// ---------------- fp32 -> bf16 convert ----------------
__global__ void k_tobf(const float* __restrict__ X, unsigned short* __restrict__ Y,
                       int total) {
  int i = blockIdx.x * 256 + threadIdx.x;
  if (i < total) Y[i] = f2bf(X[i]);
}

// ---- pack W [K,128] fp32 into MFMA B-fragment order, bf16 ----
__global__ void k_wpack(const float* __restrict__ W, unsigned short* __restrict__ Wf,
                        int K) {
  int i = blockIdx.x * 256 + threadIdx.x;
  int total = (K >> 5) * 4096;
  if (i >= total) return;
  int j    = i & 7;
  int lane = (i >> 3) & 63;
  int t    = (i >> 9) & 7;
  int ks   = i >> 12;
  int k = ks * 32 + (lane >> 4) * 8 + j;
  int c = t * 16 + (lane & 15);
  Wf[i] = f2bf(W[k * 128 + c]);
}

// ============ MFMA GEMM + fused alpha: [n,K] bf16 @ Wf -> Hb bf16, AS, AD ===
// wave computes 16 rows x 128 cols; row kg*4+reg lives in lanes [kg*16,kg*16+16)
// at reg slot; col = t*16+ln. a_s flat index t*16+ln == (head,chan) for both
// HEADS=8 (cph=16, head==t) and HEADS=1 (cph=128).
template<int K, int HEADS>
__global__ __launch_bounds__(256) void k_mgemm(const short* __restrict__ Xb,
                                               const short* __restrict__ Wf,
                                               const float* __restrict__ a_s,
                                               const float* __restrict__ a_d,
                                               unsigned short* __restrict__ Y,
                                               float* __restrict__ AS,
                                               float* __restrict__ AD, int n) {
  int wv   = threadIdx.x >> 6;
  int lane = threadIdx.x & 63;
  int r0   = blockIdx.x * 64 + wv * 16;
  int ln = lane & 15, kg = lane >> 4;
  f32x4 acc[8] = {};
  int arow = min(r0 + ln, n - 1);
  const short* aptr = Xb + arow * K + kg * 8;
  #pragma unroll
  for (int ks = 0; ks < K / 32; ++ks) {
    short8v a = *(const short8v*)(aptr + ks * 32);
    const short* wp = Wf + ks * 4096 + lane * 8;
    #pragma unroll
    for (int t = 0; t < 8; ++t) {
      short8v b = *(const short8v*)(wp + t * 512);
      acc[t] = __builtin_amdgcn_mfma_f32_16x16x32_bf16(a, b, acc[t], 0, 0, 0);
    }
  }
  float asv[8], adv[8];
  #pragma unroll
  for (int t = 0; t < 8; ++t) { asv[t] = a_s[t * 16 + ln]; adv[t] = a_d[t * 16 + ln]; }
  #pragma unroll
  for (int reg = 0; reg < 4; ++reg) {
    int r = r0 + kg * 4 + reg;
    bool valid = (r < n);
    if (HEADS == 1) {
      float s1 = 0.f, s2 = 0.f;
      #pragma unroll
      for (int t = 0; t < 8; ++t) {
        s1 = fmaf(acc[t][reg], asv[t], s1);
        s2 = fmaf(acc[t][reg], adv[t], s2);
      }
      #pragma unroll
      for (int off = 1; off < 16; off <<= 1) {
        s1 += __shfl_xor(s1, off);
        s2 += __shfl_xor(s2, off);
      }
      if (valid && ln == 0) { AS[r] = s1; AD[r] = s2; }
    } else {
      float s1[8], s2[8];
      #pragma unroll
      for (int t = 0; t < 8; ++t) {
        s1[t] = acc[t][reg] * asv[t];
        s2[t] = acc[t][reg] * adv[t];
      }
      #pragma unroll
      for (int off = 1; off < 16; off <<= 1) {
        #pragma unroll
        for (int t = 0; t < 8; ++t) {
          s1[t] += __shfl_xor(s1[t], off);
          s2[t] += __shfl_xor(s2[t], off);
        }
      }
      // lane ln<8 writes head ln (static select chain; all lanes hold all sums)
      float w1 = s1[0], w2 = s2[0];
      #pragma unroll
      for (int t = 1; t < 8; ++t) {
        w1 = (ln == t) ? s1[t] : w1;
        w2 = (ln == t) ? s2[t] : w2;
      }
      if (valid && ln < 8) { AS[r * 8 + ln] = w1; AD[r * 8 + ln] = w2; }
    }
  }
  #pragma unroll
  for (int t = 0; t < 8; ++t) {
    #pragma unroll
    for (int reg = 0; reg < 4; ++reg) {
      int r = r0 + kg * 4 + reg;
      if (r < n) Y[r * 128 + t * 16 + ln] = f2bf(acc[t][reg]);
    }
  }
}

// ---- GAT aggregation: HALF-WAVE per dst, 4 ch/lane, cooperative no-max
// ---- softmax, deep load batching; + bias + ELU + LN + residual; bf16 I/O
template<int LOGC>
__global__ __launch_bounds__(256) void k_agg_post(const unsigned short* __restrict__ Hu,
    const int* __restrict__ row_off, const int* __restrict__ csr_src,
    const float* __restrict__ AS, const float* __restrict__ AD,
    const float* __restrict__ bias, const unsigned short* __restrict__ RES,
    const float* __restrict__ gamma, const float* __restrict__ beta,
    unsigned short* __restrict__ Yb, int n, int has_res) {
  int tid = blockIdx.x * 256 + threadIdx.x;
  int wid = tid >> 5;                      // half-wave (32 lanes) per node
  int ll  = threadIdx.x & 31;
  if (wid >= n) return;
  constexpr int NH  = HID >> LOGC;
  constexpr int SEG = (LOGC >= 7) ? 32 : (1 << (LOGC - 2));
  int abslane = threadIdx.x & 63;
  int c = ll << 2;
  int h = c >> LOGC;
  int r = ll & (SEG - 1);
  int sbase = abslane & ~(SEG - 1);
  float adv = AD[wid * NH + h];
  int jb = row_off[wid], je = row_off[wid + 1];
  float den = 0.f, a0 = 0.f, a1 = 0.f, a2 = 0.f, a3 = 0.f;
  for (int j0 = jb; j0 < je; j0 += SEG) {
    int cnt = min(SEG, je - j0);
    int s_l = 0; float p_l = 0.f;
    if (r < cnt) {
      s_l = csr_src[j0 + r];
      float e = AS[s_l * NH + h] + adv;
      e = (e > 0.f) ? e : 0.2f * e;
      p_l = __expf(e);
    }
    int k = 0;
    if (LOGC >= 7) {
      for (; k + 8 <= cnt; k += 8) {       // 8-deep: 8 loads in flight
        int   sk[8]; float pk[8]; ushort4 uu[8];
        #pragma unroll
        for (int q = 0; q < 8; ++q) sk[q] = __shfl(s_l, sbase | (k + q));
        #pragma unroll
        for (int q = 0; q < 8; ++q) uu[q] = *(const ushort4*)(Hu + (sk[q] << 7) + c);
        #pragma unroll
        for (int q = 0; q < 8; ++q) pk[q] = __shfl(p_l, sbase | (k + q));
        #pragma unroll
        for (int q = 0; q < 8; ++q) {
          den += pk[q];
          a0 = fmaf(pk[q], bf2f(uu[q].x), a0);
          a1 = fmaf(pk[q], bf2f(uu[q].y), a1);
          a2 = fmaf(pk[q], bf2f(uu[q].z), a2);
          a3 = fmaf(pk[q], bf2f(uu[q].w), a3);
        }
      }
    }
    for (; k + 4 <= cnt; k += 4) {
      int sk0 = __shfl(s_l, sbase | k);
      int sk1 = __shfl(s_l, sbase | (k + 1));
      int sk2 = __shfl(s_l, sbase | (k + 2));
      int sk3 = __shfl(s_l, sbase | (k + 3));
      ushort4 u0 = *(const ushort4*)(Hu + (sk0 << 7) + c);
      ushort4 u1 = *(const ushort4*)(Hu + (sk1 << 7) + c);
      ushort4 u2 = *(const ushort4*)(Hu + (sk2 << 7) + c);
      ushort4 u3 = *(const ushort4*)(Hu + (sk3 << 7) + c);
      float p0 = __shfl(p_l, sbase | k);
      float p1 = __shfl(p_l, sbase | (k + 1));
      float p2 = __shfl(p_l, sbase | (k + 2));
      float p3 = __shfl(p_l, sbase | (k + 3));
      den += (p0 + p1) + (p2 + p3);
      a0 = fmaf(p0, bf2f(u0.x), a0); a1 = fmaf(p0, bf2f(u0.y), a1);
      a2 = fmaf(p0, bf2f(u0.z), a2); a3 = fmaf(p0, bf2f(u0.w), a3);
      a0 = fmaf(p1, bf2f(u1.x), a0); a1 = fmaf(p1, bf2f(u1.y), a1);
      a2 = fmaf(p1, bf2f(u1.z), a2); a3 = fmaf(p1, bf2f(u1.w), a3);
      a0 = fmaf(p2, bf2f(u2.x), a0); a1 = fmaf(p2, bf2f(u2.y), a1);
      a2 = fmaf(p2, bf2f(u2.z), a2); a3 = fmaf(p2, bf2f(u2.w), a3);
      a0 = fmaf(p3, bf2f(u3.x), a0); a1 = fmaf(p3, bf2f(u3.y), a1);
      a2 = fmaf(p3, bf2f(u3.z), a2); a3 = fmaf(p3, bf2f(u3.w), a3);
    }
    for (; k < cnt; ++k) {
      int   s  = __shfl(s_l, sbase | k);
      float pk = __shfl(p_l, sbase | k);
      ushort4 u = *(const ushort4*)(Hu + (s << 7) + c);
      den += pk;
      a0 = fmaf(pk, bf2f(u.x), a0); a1 = fmaf(pk, bf2f(u.y), a1);
      a2 = fmaf(pk, bf2f(u.z), a2); a3 = fmaf(pk, bf2f(u.w), a3);
    }
  }
  float inv = 1.f / (den + 1e-16f);
  float4 bv = *(const float4*)(bias + c);
  float t0 = a0 * inv + bv.x;
  float t1 = a1 * inv + bv.y;
  float t2 = a2 * inv + bv.z;
  float t3 = a3 * inv + bv.w;
  float e0 = t0 > 0.f ? t0 : __expf(t0) - 1.f;
  float e1 = t1 > 0.f ? t1 : __expf(t1) - 1.f;
  float e2 = t2 > 0.f ? t2 : __expf(t2) - 1.f;
  float e3 = t3 > 0.f ? t3 : __expf(t3) - 1.f;
  float s1 = (e0 + e1) + (e2 + e3);
  float s2 = (e0 * e0 + e1 * e1) + (e2 * e2 + e3 * e3);
  #pragma unroll
  for (int off = 16; off >= 1; off >>= 1) {
    s1 += __shfl_xor(s1, off);
    s2 += __shfl_xor(s2, off);
  }
  float mu  = s1 * (1.f / 128.f);
  float var = s2 * (1.f / 128.f) - mu * mu;
  float rs  = rsqrtf(var + 1e-5f);
  int base = wid * HID;
  float r0 = 0.f, r1 = 0.f, r2 = 0.f, r3 = 0.f;
  if (has_res) {
    ushort4 rv = *(const ushort4*)(RES + base + c);
    r0 = bf2f(rv.x); r1 = bf2f(rv.y); r2 = bf2f(rv.z); r3 = bf2f(rv.w);
  }
  float4 gv = *(const float4*)(gamma + c);
  float4 betv = *(const float4*)(beta + c);
  ushort4 ob;
  ob.x = f2bf((e0 - mu) * rs * gv.x + betv.x + r0);
  ob.y = f2bf((e1 - mu) * rs * gv.y + betv.y + r1);
  ob.z = f2bf((e2 - mu) * rs * gv.z + betv.z + r2);
  ob.w = f2bf((e3 - mu) * rs * gv.w + betv.w + r3);
  *(ushort4*)(Yb + base + c) = ob;
}

// ---------------- global mean pool: wave per graph, bf16 input ----------------
__global__ __launch_bounds__(256) void k_pool_seg(const unsigned short* __restrict__ Hf,
    const int* __restrict__ batch, float* __restrict__ pool, int n, int G) {
  int wid  = (int)((blockIdx.x * (size_t)blockDim.x + threadIdx.x) >> 6);
  int lane = threadIdx.x & 63;
  if (wid >= G) return;
  int lo = 0, hi = n;
  while (lo < hi) { int mid = (lo + hi) >> 1; if (batch[mid] < wid) lo = mid + 1; else hi = mid; }
  int start = lo;
  hi = n;
  while (lo < hi) { int mid = (lo + hi) >> 1; if (batch[mid] < wid + 1) lo = mid + 1; else hi = mid; }
  int end = lo;
  int c = 2 * lane;
  float s0 = 0.f, s1 = 0.f;
  for (int i = start; i < end; ++i) {
    ushort2 v = *(const ushort2*)(Hf + (size_t)i * HID + c);
    s0 += bf2f(v.x); s1 += bf2f(v.y);
  }
  float inv = 1.f / (float)max(end - start, 1);
  pool[(size_t)wid * HID + c]     = s0 * inv;
  pool[(size_t)wid * HID + c + 1] = s1 * inv;
}

// ---------------- small MLP: [rows,128] @ [128,128] + b (opt ELU) ----------------
__global__ void k_mlp(const float* __restrict__ X, const float* __restrict__ Wt,
                      const float* __restrict__ bb, float* __restrict__ Y,
                      int rows, int do_elu) {
  int i = blockIdx.x * blockDim.x + threadIdx.x;
  if (i >= rows * HID) return;
  int r = i >> 7, c = i & 127;
  const float* xr = X + (size_t)r * HID;
  float acc = bb[c];
  for (int k = 0; k < HID; ++k) acc += xr[k] * Wt[k * HID + c];
  if (do_elu) acc = acc > 0.f ? acc : __expf(acc) - 1.f;
  Y[i] = acc;
}

extern "C" void kernel_launch(void* const* d_in, const int* in_sizes, int n_in,
                              void* d_out, int out_size, void* d_ws, size_t ws_size,
                              hipStream_t stream) {
  const float* x   = (const float*)d_in[0];
  const int*   ei  = (const int*)d_in[1];
  const int*   bat = (const int*)d_in[2];
  const float* W1  = (const float*)d_in[3];
  const float* as1 = (const float*)d_in[4];
  const float* ad1 = (const float*)d_in[5];
  const float* b1  = (const float*)d_in[6];
  const float* W2  = (const float*)d_in[7];
  const float* as2 = (const float*)d_in[8];
  const float* ad2 = (const float*)d_in[9];
  const float* b2  = (const float*)d_in[10];
  const float* W3  = (const float*)d_in[11];
  const float* as3 = (const float*)d_in[12];
  const float* ad3 = (const float*)d_in[13];
  const float* b3  = (const float*)d_in[14];
  const float* g1  = (const float*)d_in[15];
  const float* be1 = (const float*)d_in[16];
  const float* g2  = (const float*)d_in[17];
  const float* be2 = (const float*)d_in[18];
  const float* g3  = (const float*)d_in[19];
  const float* be3 = (const float*)d_in[20];
  const float* lw1 = (const float*)d_in[21];
  const float* lb1 = (const float*)d_in[22];
  const float* lw2 = (const float*)d_in[23];
  const float* lb2 = (const float*)d_in[24];

  int N = in_sizes[0] / F_IN;
  int E = in_sizes[1] / 2;
  int G = out_size / HID;
  int tot = E + N;
  int nb  = (N + 127) >> 7;          // buckets (<=1024)

  char* p = (char*)d_ws;
  auto alloc = [&](size_t bytes) { char* r = p; p += (bytes + 511) & ~(size_t)511; return r; };
  int*   bcnt    = (int*)  alloc(1024 * 4);
  int*   boff    = (int*)  alloc(1025 * 4);
  int*   bcur    = (int*)  alloc(1024 * 4);
  int*   row_off = (int*)  alloc((size_t)(N + 1) * 4);
  int*   csr_src = (int*)  alloc((size_t)tot * 4);
  uint2* pairs   = (uint2*)alloc((size_t)tot * 8);    // dead after k_bfin
  float* AS      = (float*)alloc((size_t)N * 8 * 4);
  float* AD      = (float*)alloc((size_t)N * 8 * 4);
  unsigned short* Hb  = (unsigned short*)alloc((size_t)N * HID * 2);
  unsigned short* Fb0 = (unsigned short*)alloc((size_t)N * HID * 2);
  unsigned short* Fb1 = (unsigned short*)alloc((size_t)N * HID * 2);
  unsigned short* Fb2 = (unsigned short*)alloc((size_t)N * HID * 2);
  float* pool    = (float*)alloc((size_t)G * HID * 4);
  float* t1      = (float*)alloc((size_t)G * HID * 4);
  unsigned short* Wf1 = (unsigned short*)alloc(64 * 128 * 2);
  unsigned short* Wf2 = (unsigned short*)alloc(128 * 128 * 2);
  unsigned short* Wf3 = (unsigned short*)alloc(128 * 128 * 2);
  unsigned short* xb  = (unsigned short*)pairs;       // alias dead pairs buffer

  (void)hipMemsetAsync(bcnt, 0, 1024 * 4, stream);

  int sb = (tot + SCHUNK - 1) / SCHUNK;
  k_bhist<<<256, 256, 0, stream>>>(ei, bcnt, E, N);
  k_bscan<<<1, 1024, 0, stream>>>(bcnt, boff, bcur, nb);
  k_bscat<<<sb, 256, 0, stream>>>(ei, bcur, pairs, E, N);
  k_bfin <<<nb, 256, 0, stream>>>(pairs, boff, row_off, csr_src, N, tot);

  // prep for MFMA gemms (pairs is dead now; xb aliases it)
  k_tobf <<<(N * F_IN + 255) / 256, 256, 0, stream>>>(x, xb, N * F_IN);
  k_wpack<<<(64 * 128 + 255) / 256, 256, 0, stream>>>(W1, Wf1, 64);
  k_wpack<<<(128 * 128 + 255) / 256, 256, 0, stream>>>(W2, Wf2, 128);
  k_wpack<<<(128 * 128 + 255) / 256, 256, 0, stream>>>(W3, Wf3, 128);

  int mb  = (N + 63) / 64;                // MFMA GEMM blocks (64 rows each)
  int nh2 = (N + 7) / 8;                  // half-wave-per-node agg

  // ---- layer 1
  k_mgemm<64, 8><<<mb, 256, 0, stream>>>((const short*)xb, (const short*)Wf1,
                                         as1, ad1, Hb, AS, AD, N);
  k_agg_post<4><<<nh2, 256, 0, stream>>>(Hb, row_off, csr_src, AS, AD, b1,
                                         nullptr, g1, be1, Fb0, N, 0);

  // ---- layer 2
  k_mgemm<128, 1><<<mb, 256, 0, stream>>>((const short*)Fb0, (const short*)Wf2,
                                          as2, ad2, Hb, AS, AD, N);
  k_agg_post<7><<<nh2, 256, 0, stream>>>(Hb, row_off, csr_src, AS, AD, b2,
                                         Fb0, g2, be2, Fb1, N, 1);

  // ---- layer 3
  k_mgemm<128, 1><<<mb, 256, 0, stream>>>((const short*)Fb1, (const short*)Wf3,
                                          as3, ad3, Hb, AS, AD, N);
  k_agg_post<7><<<nh2, 256, 0, stream>>>(Hb, row_off, csr_src, AS, AD, b3,
                                         Fb1, g3, be3, Fb2, N, 1);

  // ---- pool + MLP head
  k_pool_seg<<<(G + 3) / 4, 256, 0, stream>>>(Fb2, bat, pool, N, G);
  k_mlp<<<(G * HID + 255) / 256, 256, 0, stream>>>(pool, lw1, lb1, t1, G, 1);
  k_mlp<<<(G * HID + 255) / 256, 256, 0, stream>>>(t1, lw2, lb2, (float*)d_out, G, 0);
}